// Round 1
// baseline (498.703 us; speedup 1.0000x reference)
//
#include <hip/hip_runtime.h>
#include <hip/hip_bf16.h>
#include <math.h>

// ---------------------------------------------------------------------------
// GCN(2 layers, fused norm) -> mean-pool -> LSTM step (h0=c0=0) -> heads
// ---------------------------------------------------------------------------

__global__ void count_deg_kernel(const int* __restrict__ dst, int E, int* __restrict__ deg) {
    int e = blockIdx.x * blockDim.x + threadIdx.x;
    if (e < E) atomicAdd(&deg[dst[e]], 1);
}

// block scans 1024 elements (256 threads x 4)
__global__ void scan_pass1(const int* __restrict__ deg, int n,
                           int* __restrict__ rowptr, int* __restrict__ bsums) {
    __shared__ int s[256];
    int tid = threadIdx.x;
    int base = blockIdx.x * 1024;
    int v[4];
    int mysum = 0;
#pragma unroll
    for (int j = 0; j < 4; ++j) {
        int idx = base + tid * 4 + j;
        v[j] = (idx < n) ? deg[idx] : 0;
        mysum += v[j];
    }
    s[tid] = mysum;
    __syncthreads();
    for (int off = 1; off < 256; off <<= 1) {
        int t = (tid >= off) ? s[tid - off] : 0;
        __syncthreads();
        s[tid] += t;
        __syncthreads();
    }
    int excl = s[tid] - mysum;
#pragma unroll
    for (int j = 0; j < 4; ++j) {
        int idx = base + tid * 4 + j;
        if (idx < n) rowptr[idx] = excl;
        excl += v[j];
    }
    if (tid == 255) bsums[blockIdx.x] = s[255];
}

// scan up to 64 block sums (nb <= 64), exclusive; bsums[nb] = total
__global__ void scan_pass2(int* bsums, int nb) {
    __shared__ int s[64];
    int tid = threadIdx.x;
    int v = (tid < nb) ? bsums[tid] : 0;
    s[tid] = v;
    __syncthreads();
    for (int off = 1; off < 64; off <<= 1) {
        int t = (tid >= off) ? s[tid - off] : 0;
        __syncthreads();
        s[tid] += t;
        __syncthreads();
    }
    if (tid < nb) bsums[tid] = s[tid] - v;
    if (tid == 63) bsums[nb] = s[63];
}

__global__ void scan_pass3(int* __restrict__ rowptr, const int* __restrict__ bsums, int n, int nb) {
    int tid = threadIdx.x;
    int base = blockIdx.x * 1024;
    int add = bsums[blockIdx.x];
#pragma unroll
    for (int j = 0; j < 4; ++j) {
        int idx = base + tid * 4 + j;
        if (idx < n) rowptr[idx] += add;
    }
    if (blockIdx.x == 0 && tid == 0) rowptr[n] = bsums[nb];
}

__global__ void fill_csr_kernel(const int* __restrict__ src, const int* __restrict__ dst, int E,
                                const int* __restrict__ rowptr, int* __restrict__ cursor,
                                int* __restrict__ csr) {
    int e = blockIdx.x * blockDim.x + threadIdx.x;
    if (e < E) {
        int d = dst[e];
        int pos = rowptr[d] + atomicAdd(&cursor[d], 1);
        csr[pos] = src[e];
    }
}

__global__ void dinv_kernel(const int* __restrict__ deg, float* __restrict__ dinv, int n) {
    int i = blockIdx.x * blockDim.x + threadIdx.x;
    if (i < n) dinv[i] = rsqrtf((float)deg[i] + 1.0f);  // +1 self loop; always > 0
}

// out[r][c] = dinv[r] * sum_k A[r][k]*W[k][c]   (A: n x 128, W: 128 x 128 row-major)
__global__ __launch_bounds__(256) void gemm_scale_kernel(const float* __restrict__ A,
                                                         const float* __restrict__ W,
                                                         const float* __restrict__ dinv,
                                                         float* __restrict__ out, int n) {
    __shared__ __align__(16) float Ws[128 * 128];  // 64 KB
    __shared__ __align__(16) float Xs[64 * 128];   // 32 KB
    int tid = threadIdx.x;
    int rowbase = blockIdx.x * 64;
    {
        const float4* W4 = (const float4*)W;
        float4* Ws4 = (float4*)Ws;
#pragma unroll
        for (int i = 0; i < 16; ++i) Ws4[tid + 256 * i] = W4[tid + 256 * i];
        const float4* A4 = (const float4*)(A + (size_t)rowbase * 128);
        float4* Xs4 = (float4*)Xs;
        int nrow = n - rowbase; if (nrow > 64) nrow = 64;
        int maxv = nrow * 32;
#pragma unroll
        for (int i = 0; i < 8; ++i) {
            int idx = tid + 256 * i;
            float4 z = make_float4(0.f, 0.f, 0.f, 0.f);
            Xs4[idx] = (idx < maxv) ? A4[idx] : z;
        }
    }
    __syncthreads();
    int tx = tid & 31, ty = tid >> 5;
    int c0 = tx * 4, r0 = ty * 8;
    float acc[8][4];
#pragma unroll
    for (int r = 0; r < 8; ++r) { acc[r][0] = acc[r][1] = acc[r][2] = acc[r][3] = 0.f; }
#pragma unroll 2
    for (int kk = 0; kk < 128; kk += 4) {
        float4 wb0 = *(const float4*)&Ws[(kk + 0) * 128 + c0];
        float4 wb1 = *(const float4*)&Ws[(kk + 1) * 128 + c0];
        float4 wb2 = *(const float4*)&Ws[(kk + 2) * 128 + c0];
        float4 wb3 = *(const float4*)&Ws[(kk + 3) * 128 + c0];
#pragma unroll
        for (int r = 0; r < 8; ++r) {
            float4 xa = *(const float4*)&Xs[(r0 + r) * 128 + kk];
            acc[r][0] += xa.x * wb0.x + xa.y * wb1.x + xa.z * wb2.x + xa.w * wb3.x;
            acc[r][1] += xa.x * wb0.y + xa.y * wb1.y + xa.z * wb2.y + xa.w * wb3.y;
            acc[r][2] += xa.x * wb0.z + xa.y * wb1.z + xa.z * wb2.z + xa.w * wb3.z;
            acc[r][3] += xa.x * wb0.w + xa.y * wb1.w + xa.z * wb2.w + xa.w * wb3.w;
        }
    }
#pragma unroll
    for (int r = 0; r < 8; ++r) {
        int row = rowbase + r0 + r;
        if (row < n) {
            float s = dinv[row];
            float4 o = make_float4(acc[r][0] * s, acc[r][1] * s, acc[r][2] * s, acc[r][3] * s);
            *(float4*)&out[(size_t)row * 128 + c0] = o;
        }
    }
}

// out[i] = relu(dinv[i] * (sum_{e in in(i)} g[src_e] + g[i]) + bias)
// one wave (64 lanes) per node, lane owns float2 of the 128 features
__global__ __launch_bounds__(256) void aggregate_kernel(const float* __restrict__ g,
                                                        const int* __restrict__ rowptr,
                                                        const int* __restrict__ csr,
                                                        const float* __restrict__ dinv,
                                                        const float* __restrict__ bias,
                                                        float* __restrict__ out, int n) {
    int lane = threadIdx.x & 63;
    int node = (blockIdx.x * blockDim.x + threadIdx.x) >> 6;
    if (node >= n) return;
    int beg = rowptr[node], end = rowptr[node + 1];
    const float2* __restrict__ g2 = (const float2*)g;
    float2 acc = g2[(size_t)node * 64 + lane];  // self-loop term
    int e = beg;
    for (; e + 4 <= end; e += 4) {
        int s0 = csr[e + 0], s1 = csr[e + 1], s2 = csr[e + 2], s3 = csr[e + 3];
        float2 v0 = g2[(size_t)s0 * 64 + lane];
        float2 v1 = g2[(size_t)s1 * 64 + lane];
        float2 v2 = g2[(size_t)s2 * 64 + lane];
        float2 v3 = g2[(size_t)s3 * 64 + lane];
        acc.x += v0.x + v1.x + v2.x + v3.x;
        acc.y += v0.y + v1.y + v2.y + v3.y;
    }
    for (; e < end; ++e) {
        int s0 = csr[e];
        float2 v0 = g2[(size_t)s0 * 64 + lane];
        acc.x += v0.x;
        acc.y += v0.y;
    }
    float dv = dinv[node];
    float2 b = ((const float2*)bias)[lane];
    float2 r;
    r.x = fmaxf(dv * acc.x + b.x, 0.f);
    r.y = fmaxf(dv * acc.y + b.y, 0.f);
    ((float2*)out)[(size_t)node * 64 + lane] = r;
}

// one block per graph; batch is sorted -> binary search boundaries
__global__ void pool_kernel(const float* __restrict__ h, const int* __restrict__ batch, int n,
                            float* __restrict__ pooled) {
    int gidx = blockIdx.x;
    int tid = threadIdx.x;  // 128 threads, one feature each
    int lo = 0, hi = n;
    while (lo < hi) { int mid = (lo + hi) >> 1; if (batch[mid] < gidx) lo = mid + 1; else hi = mid; }
    int start = lo;
    hi = n;
    while (lo < hi) { int mid = (lo + hi) >> 1; if (batch[mid] < gidx + 1) lo = mid + 1; else hi = mid; }
    int end = lo;
    float acc = 0.f;
    for (int i = start; i < end; ++i) acc += h[(size_t)i * 128 + tid];
    pooled[gidx * 128 + tid] = acc / fmaxf((float)(end - start), 1.0f);
}

// one block (256 threads) per graph; thread t owns hidden unit t.
// gates order i,f,g,o ; f is dead (c0=0). W_hh term dead (h0=0).
__global__ __launch_bounds__(256) void lstm_head_kernel(const float* __restrict__ pooled,
                                                        const float* __restrict__ W_ih,
                                                        const float* __restrict__ b_ih,
                                                        const float* __restrict__ b_hh,
                                                        const float* __restrict__ Wm,
                                                        const float* __restrict__ bm,
                                                        const float* __restrict__ Wv,
                                                        const float* __restrict__ bv,
                                                        float* __restrict__ out) {
    __shared__ __align__(16) float p[128];
    __shared__ float redm[256];
    __shared__ float redv[256];
    int gph = blockIdx.x;
    int tid = threadIdx.x;
    if (tid < 128) p[tid] = pooled[gph * 128 + tid];
    __syncthreads();
    float gi = b_ih[tid] + b_hh[tid];
    float gg = b_ih[512 + tid] + b_hh[512 + tid];
    float go = b_ih[768 + tid] + b_hh[768 + tid];
    const float4* wi = (const float4*)(W_ih + (size_t)tid * 128);
    const float4* wg = (const float4*)(W_ih + (size_t)(512 + tid) * 128);
    const float4* wo = (const float4*)(W_ih + (size_t)(768 + tid) * 128);
    const float4* p4 = (const float4*)p;
#pragma unroll 8
    for (int k = 0; k < 32; ++k) {
        float4 xv = p4[k];
        float4 a = wi[k], bq = wg[k], cq = wo[k];
        gi += xv.x * a.x + xv.y * a.y + xv.z * a.z + xv.w * a.w;
        gg += xv.x * bq.x + xv.y * bq.y + xv.z * bq.z + xv.w * bq.w;
        go += xv.x * cq.x + xv.y * cq.y + xv.z * cq.z + xv.w * cq.w;
    }
    float iv = 1.f / (1.f + expf(-gi));
    float cv = iv * tanhf(gg);
    float ov = 1.f / (1.f + expf(-go));
    float hT = ov * tanhf(cv);
    redm[tid] = hT * Wm[tid];
    redv[tid] = hT * Wv[tid];
    __syncthreads();
    for (int s = 128; s > 0; s >>= 1) {
        if (tid < s) { redm[tid] += redm[tid + s]; redv[tid] += redv[tid + s]; }
        __syncthreads();
    }
    if (tid == 0) {
        out[gph] = redm[0] + bm[0];
        float xv = redv[0] + bv[0];
        out[64 + gph] = fmaxf(xv, 0.f) + log1pf(expf(-fabsf(xv)));  // stable softplus
    }
}

extern "C" void kernel_launch(void* const* d_in, const int* in_sizes, int n_in,
                              void* d_out, int out_size, void* d_ws, size_t ws_size,
                              hipStream_t stream) {
    const float* x     = (const float*)d_in[0];
    const int*   edge  = (const int*)d_in[1];
    const int*   batch = (const int*)d_in[2];
    const float* W1    = (const float*)d_in[3];
    const float* b1    = (const float*)d_in[4];
    const float* W2    = (const float*)d_in[5];
    const float* b2    = (const float*)d_in[6];
    const float* W_ih  = (const float*)d_in[7];
    /* d_in[8] = W_hh: dead (h0 = 0) */
    const float* b_ih  = (const float*)d_in[9];
    const float* b_hh  = (const float*)d_in[10];
    const float* Wm    = (const float*)d_in[11];
    const float* bm    = (const float*)d_in[12];
    const float* Wv    = (const float*)d_in[13];
    const float* bv    = (const float*)d_in[14];
    float* out = (float*)d_out;

    const int N = in_sizes[0] / 128;
    const int E = in_sizes[1] / 2;
    const int* srcIdx = edge;      // edge_index[0]
    const int* dstIdx = edge + E;  // edge_index[1]

    char* ws = (char*)d_ws;
    size_t off = 0;
    const size_t fB = (size_t)N * 128 * sizeof(float);
    float* gbuf = (float*)(ws + off); off += fB;
    float* hbuf = (float*)(ws + off); off += fB;
    int* deg    = (int*)(ws + off);   off += (size_t)N * sizeof(int);
    int* cursor = (int*)(ws + off);   off += (size_t)N * sizeof(int);  // adjacent to deg
    int* rowptr = (int*)(ws + off);   off += (size_t)(N + 1) * sizeof(int);
    off = (off + 255) & ~(size_t)255;
    int* bsums  = (int*)(ws + off);   off += 512;
    int* csr    = (int*)(ws + off);   off += (size_t)E * sizeof(int);
    off = (off + 255) & ~(size_t)255;
    float* dinv = (float*)(ws + off); off += (size_t)N * sizeof(float);
    off = (off + 255) & ~(size_t)255;
    float* pooled = (float*)(ws + off); off += 64 * 128 * sizeof(float);

    // zero deg + cursor (contiguous)
    hipMemsetAsync(deg, 0, (size_t)2 * N * sizeof(int), stream);

    int eb = (E + 255) / 256;
    count_deg_kernel<<<eb, 256, 0, stream>>>(dstIdx, E, deg);

    int nb = (N + 1023) / 1024;  // 49 for N=50000 (<=64 required by scan_pass2)
    scan_pass1<<<nb, 256, 0, stream>>>(deg, N, rowptr, bsums);
    scan_pass2<<<1, 64, 0, stream>>>(bsums, nb);
    scan_pass3<<<nb, 256, 0, stream>>>(rowptr, bsums, N, nb);
    dinv_kernel<<<(N + 255) / 256, 256, 0, stream>>>(deg, dinv, N);
    fill_csr_kernel<<<eb, 256, 0, stream>>>(srcIdx, dstIdx, E, rowptr, cursor, csr);

    int gb = (N + 63) / 64;
    int ab = (N + 3) / 4;  // 4 waves (nodes) per 256-thread block

    // layer 1
    gemm_scale_kernel<<<gb, 256, 0, stream>>>(x, W1, dinv, gbuf, N);
    aggregate_kernel<<<ab, 256, 0, stream>>>(gbuf, rowptr, csr, dinv, b1, hbuf, N);
    // layer 2
    gemm_scale_kernel<<<gb, 256, 0, stream>>>(hbuf, W2, dinv, gbuf, N);
    aggregate_kernel<<<ab, 256, 0, stream>>>(gbuf, rowptr, csr, dinv, b2, hbuf, N);

    // pooling + LSTM + heads
    pool_kernel<<<64, 128, 0, stream>>>(hbuf, batch, N, pooled);
    lstm_head_kernel<<<64, 256, 0, stream>>>(pooled, W_ih, b_ih, b_hh, Wm, bm, Wv, bv, out);
}

// Round 4
// 312.044 us; speedup vs baseline: 1.5982x; 1.5982x over previous
//
#include <hip/hip_runtime.h>
#include <hip/hip_bf16.h>
#include <math.h>

// ---------------------------------------------------------------------------
// GCN(2 layers, fused norm) -> mean-pool -> LSTM step (h0=c0=0) -> heads
// ---------------------------------------------------------------------------

#define POOL_SUB 32

__global__ void count_deg_kernel(const int* __restrict__ dst, int E, int* __restrict__ deg) {
    int e = blockIdx.x * blockDim.x + threadIdx.x;
    if (e < E) atomicAdd(&deg[dst[e]], 1);
}

// block scans 1024 elements (256 threads x 4)
__global__ void scan_pass1(const int* __restrict__ deg, int n,
                           int* __restrict__ rowptr, int* __restrict__ bsums) {
    __shared__ int s[256];
    int tid = threadIdx.x;
    int base = blockIdx.x * 1024;
    int v[4];
    int mysum = 0;
#pragma unroll
    for (int j = 0; j < 4; ++j) {
        int idx = base + tid * 4 + j;
        v[j] = (idx < n) ? deg[idx] : 0;
        mysum += v[j];
    }
    s[tid] = mysum;
    __syncthreads();
    for (int off = 1; off < 256; off <<= 1) {
        int t = (tid >= off) ? s[tid - off] : 0;
        __syncthreads();
        s[tid] += t;
        __syncthreads();
    }
    int excl = s[tid] - mysum;
#pragma unroll
    for (int j = 0; j < 4; ++j) {
        int idx = base + tid * 4 + j;
        if (idx < n) rowptr[idx] = excl;
        excl += v[j];
    }
    if (tid == 255) bsums[blockIdx.x] = s[255];
}

// scan up to 64 block sums (nb <= 64), exclusive; bsums[nb] = total
__global__ void scan_pass2(int* bsums, int nb) {
    __shared__ int s[64];
    int tid = threadIdx.x;
    int v = (tid < nb) ? bsums[tid] : 0;
    s[tid] = v;
    __syncthreads();
    for (int off = 1; off < 64; off <<= 1) {
        int t = (tid >= off) ? s[tid - off] : 0;
        __syncthreads();
        s[tid] += t;
        __syncthreads();
    }
    if (tid < nb) bsums[tid] = s[tid] - v;
    if (tid == 63) bsums[nb] = s[63];
}

__global__ void scan_pass3(int* __restrict__ rowptr, const int* __restrict__ bsums, int n, int nb) {
    int tid = threadIdx.x;
    int base = blockIdx.x * 1024;
    int add = bsums[blockIdx.x];
#pragma unroll
    for (int j = 0; j < 4; ++j) {
        int idx = base + tid * 4 + j;
        if (idx < n) rowptr[idx] += add;
    }
    if (blockIdx.x == 0 && tid == 0) rowptr[n] = bsums[nb];
}

__global__ void fill_csr_kernel(const int* __restrict__ src, const int* __restrict__ dst, int E,
                                const int* __restrict__ rowptr, int* __restrict__ cursor,
                                int* __restrict__ csr) {
    int e = blockIdx.x * blockDim.x + threadIdx.x;
    if (e < E) {
        int d = dst[e];
        int pos = rowptr[d] + atomicAdd(&cursor[d], 1);
        csr[pos] = src[e];
    }
}

__global__ void dinv_kernel(const int* __restrict__ deg, float* __restrict__ dinv, int n) {
    int i = blockIdx.x * blockDim.x + threadIdx.x;
    if (i < n) dinv[i] = rsqrtf((float)deg[i] + 1.0f);  // +1 self loop; always > 0
}

// out[r][c] = dinv[r] * sum_k A[r][k]*W[k][c]   (A: n x 128, W: 128 x 128 row-major)
__global__ __launch_bounds__(256) void gemm_scale_kernel(const float* __restrict__ A,
                                                         const float* __restrict__ W,
                                                         const float* __restrict__ dinv,
                                                         float* __restrict__ out, int n) {
    __shared__ __align__(16) float Ws[128 * 128];  // 64 KB
    __shared__ __align__(16) float Xs[64 * 128];   // 32 KB
    int tid = threadIdx.x;
    int rowbase = blockIdx.x * 64;
    {
        const float4* W4 = (const float4*)W;
        float4* Ws4 = (float4*)Ws;
#pragma unroll
        for (int i = 0; i < 16; ++i) Ws4[tid + 256 * i] = W4[tid + 256 * i];
        const float4* A4 = (const float4*)(A + (size_t)rowbase * 128);
        float4* Xs4 = (float4*)Xs;
        int nrow = n - rowbase; if (nrow > 64) nrow = 64;
        int maxv = nrow * 32;
#pragma unroll
        for (int i = 0; i < 8; ++i) {
            int idx = tid + 256 * i;
            float4 z = make_float4(0.f, 0.f, 0.f, 0.f);
            Xs4[idx] = (idx < maxv) ? A4[idx] : z;
        }
    }
    __syncthreads();
    int tx = tid & 31, ty = tid >> 5;
    int c0 = tx * 4, r0 = ty * 8;
    float acc[8][4];
#pragma unroll
    for (int r = 0; r < 8; ++r) { acc[r][0] = acc[r][1] = acc[r][2] = acc[r][3] = 0.f; }
#pragma unroll 2
    for (int kk = 0; kk < 128; kk += 4) {
        float4 wb0 = *(const float4*)&Ws[(kk + 0) * 128 + c0];
        float4 wb1 = *(const float4*)&Ws[(kk + 1) * 128 + c0];
        float4 wb2 = *(const float4*)&Ws[(kk + 2) * 128 + c0];
        float4 wb3 = *(const float4*)&Ws[(kk + 3) * 128 + c0];
#pragma unroll
        for (int r = 0; r < 8; ++r) {
            float4 xa = *(const float4*)&Xs[(r0 + r) * 128 + kk];
            acc[r][0] += xa.x * wb0.x + xa.y * wb1.x + xa.z * wb2.x + xa.w * wb3.x;
            acc[r][1] += xa.x * wb0.y + xa.y * wb1.y + xa.z * wb2.y + xa.w * wb3.y;
            acc[r][2] += xa.x * wb0.z + xa.y * wb1.z + xa.z * wb2.z + xa.w * wb3.z;
            acc[r][3] += xa.x * wb0.w + xa.y * wb1.w + xa.z * wb2.w + xa.w * wb3.w;
        }
    }
#pragma unroll
    for (int r = 0; r < 8; ++r) {
        int row = rowbase + r0 + r;
        if (row < n) {
            float s = dinv[row];
            float4 o = make_float4(acc[r][0] * s, acc[r][1] * s, acc[r][2] * s, acc[r][3] * s);
            *(float4*)&out[(size_t)row * 128 + c0] = o;
        }
    }
}

// out[i] = relu(dinv[i] * (sum_{e in in(i)} g[src_e] + g[i]) + bias)
// one wave (64 lanes) per node, lane owns float2 of the 128 features
__global__ __launch_bounds__(256) void aggregate_kernel(const float* __restrict__ g,
                                                        const int* __restrict__ rowptr,
                                                        const int* __restrict__ csr,
                                                        const float* __restrict__ dinv,
                                                        const float* __restrict__ bias,
                                                        float* __restrict__ out, int n) {
    int lane = threadIdx.x & 63;
    int node = (blockIdx.x * blockDim.x + threadIdx.x) >> 6;
    if (node >= n) return;
    int beg = rowptr[node], end = rowptr[node + 1];
    const float2* __restrict__ g2 = (const float2*)g;
    float2 acc = g2[(size_t)node * 64 + lane];  // self-loop term
    int e = beg;
    for (; e + 4 <= end; e += 4) {
        int s0 = csr[e + 0], s1 = csr[e + 1], s2 = csr[e + 2], s3 = csr[e + 3];
        float2 v0 = g2[(size_t)s0 * 64 + lane];
        float2 v1 = g2[(size_t)s1 * 64 + lane];
        float2 v2 = g2[(size_t)s2 * 64 + lane];
        float2 v3 = g2[(size_t)s3 * 64 + lane];
        acc.x += v0.x + v1.x + v2.x + v3.x;
        acc.y += v0.y + v1.y + v2.y + v3.y;
    }
    for (; e < end; ++e) {
        int s0 = csr[e];
        float2 v0 = g2[(size_t)s0 * 64 + lane];
        acc.x += v0.x;
        acc.y += v0.y;
    }
    float dv = dinv[node];
    float2 b = ((const float2*)bias)[lane];
    float2 r;
    r.x = fmaxf(dv * acc.x + b.x, 0.f);
    r.y = fmaxf(dv * acc.y + b.y, 0.f);
    ((float2*)out)[(size_t)node * 64 + lane] = r;
}

// stage 1: 64 graphs x POOL_SUB sub-blocks; each sub-block sums a fixed slice
// of the graph's row range (batch sorted -> binary search). Deterministic.
__global__ __launch_bounds__(128) void pool_partial_kernel(const float* __restrict__ h,
                                                           const int* __restrict__ batch, int n,
                                                           float* __restrict__ partial) {
    int g = blockIdx.x / POOL_SUB;
    int sub = blockIdx.x % POOL_SUB;
    int tid = threadIdx.x;  // 128 threads, one feature each
    int lo = 0, hi = n;
    while (lo < hi) { int mid = (lo + hi) >> 1; if (batch[mid] < g) lo = mid + 1; else hi = mid; }
    int start = lo;
    hi = n;
    while (lo < hi) { int mid = (lo + hi) >> 1; if (batch[mid] < g + 1) lo = mid + 1; else hi = mid; }
    int end = lo;
    int len = end - start;
    int b0 = start + (int)((long long)len * sub / POOL_SUB);
    int b1 = start + (int)((long long)len * (sub + 1) / POOL_SUB);
    float acc = 0.f;
    int i = b0;
    for (; i + 4 <= b1; i += 4) {
        float v0 = h[(size_t)(i + 0) * 128 + tid];
        float v1 = h[(size_t)(i + 1) * 128 + tid];
        float v2 = h[(size_t)(i + 2) * 128 + tid];
        float v3 = h[(size_t)(i + 3) * 128 + tid];
        acc += v0 + v1 + v2 + v3;
    }
    for (; i < b1; ++i) acc += h[(size_t)i * 128 + tid];
    partial[(size_t)blockIdx.x * 128 + tid] = acc;
}

// stage 2: 64 blocks; sum POOL_SUB partials, divide by count
__global__ __launch_bounds__(128) void pool_finish_kernel(const float* __restrict__ partial,
                                                          const int* __restrict__ batch, int n,
                                                          float* __restrict__ pooled) {
    int g = blockIdx.x;
    int tid = threadIdx.x;
    int lo = 0, hi = n;
    while (lo < hi) { int mid = (lo + hi) >> 1; if (batch[mid] < g) lo = mid + 1; else hi = mid; }
    int start = lo;
    hi = n;
    while (lo < hi) { int mid = (lo + hi) >> 1; if (batch[mid] < g + 1) lo = mid + 1; else hi = mid; }
    int end = lo;
    float acc = 0.f;
#pragma unroll
    for (int s = 0; s < POOL_SUB; ++s)
        acc += partial[(size_t)(g * POOL_SUB + s) * 128 + tid];
    pooled[g * 128 + tid] = acc / fmaxf((float)(end - start), 1.0f);
}

// one block (256 threads) per graph; thread t owns hidden unit t.
// gates order i,f,g,o ; f is dead (c0=0). W_hh term dead (h0=0).
__global__ __launch_bounds__(256) void lstm_head_kernel(const float* __restrict__ pooled,
                                                        const float* __restrict__ W_ih,
                                                        const float* __restrict__ b_ih,
                                                        const float* __restrict__ b_hh,
                                                        const float* __restrict__ Wm,
                                                        const float* __restrict__ bm,
                                                        const float* __restrict__ Wv,
                                                        const float* __restrict__ bv,
                                                        float* __restrict__ out) {
    __shared__ __align__(16) float p[128];
    __shared__ float redm[256];
    __shared__ float redv[256];
    int gph = blockIdx.x;
    int tid = threadIdx.x;
    if (tid < 128) p[tid] = pooled[gph * 128 + tid];
    __syncthreads();
    float gi = b_ih[tid] + b_hh[tid];
    float gg = b_ih[512 + tid] + b_hh[512 + tid];
    float go = b_ih[768 + tid] + b_hh[768 + tid];
    const float4* wi = (const float4*)(W_ih + (size_t)tid * 128);
    const float4* wg = (const float4*)(W_ih + (size_t)(512 + tid) * 128);
    const float4* wo = (const float4*)(W_ih + (size_t)(768 + tid) * 128);
    const float4* p4 = (const float4*)p;
#pragma unroll 8
    for (int k = 0; k < 32; ++k) {
        float4 xv = p4[k];
        float4 a = wi[k], bq = wg[k], cq = wo[k];
        gi += xv.x * a.x + xv.y * a.y + xv.z * a.z + xv.w * a.w;
        gg += xv.x * bq.x + xv.y * bq.y + xv.z * bq.z + xv.w * bq.w;
        go += xv.x * cq.x + xv.y * cq.y + xv.z * cq.z + xv.w * cq.w;
    }
    float iv = 1.f / (1.f + expf(-gi));
    float cv = iv * tanhf(gg);
    float ov = 1.f / (1.f + expf(-go));
    float hT = ov * tanhf(cv);
    redm[tid] = hT * Wm[tid];
    redv[tid] = hT * Wv[tid];
    __syncthreads();
    for (int s = 128; s > 0; s >>= 1) {
        if (tid < s) { redm[tid] += redm[tid + s]; redv[tid] += redv[tid + s]; }
        __syncthreads();
    }
    if (tid == 0) {
        out[gph] = redm[0] + bm[0];
        float xv = redv[0] + bv[0];
        out[64 + gph] = fmaxf(xv, 0.f) + log1pf(expf(-fabsf(xv)));  // stable softplus
    }
}

extern "C" void kernel_launch(void* const* d_in, const int* in_sizes, int n_in,
                              void* d_out, int out_size, void* d_ws, size_t ws_size,
                              hipStream_t stream) {
    const float* x     = (const float*)d_in[0];
    const int*   edge  = (const int*)d_in[1];
    const int*   batch = (const int*)d_in[2];
    const float* W1    = (const float*)d_in[3];
    const float* b1    = (const float*)d_in[4];
    const float* W2    = (const float*)d_in[5];
    const float* b2    = (const float*)d_in[6];
    const float* W_ih  = (const float*)d_in[7];
    /* d_in[8] = W_hh: dead (h0 = 0) */
    const float* b_ih  = (const float*)d_in[9];
    const float* b_hh  = (const float*)d_in[10];
    const float* Wm    = (const float*)d_in[11];
    const float* bm    = (const float*)d_in[12];
    const float* Wv    = (const float*)d_in[13];
    const float* bv    = (const float*)d_in[14];
    float* out = (float*)d_out;

    const int N = in_sizes[0] / 128;
    const int E = in_sizes[1] / 2;
    const int* srcIdx = edge;      // edge_index[0]
    const int* dstIdx = edge + E;  // edge_index[1]

    char* ws = (char*)d_ws;
    size_t off = 0;
    const size_t fB = (size_t)N * 128 * sizeof(float);
    float* gbuf = (float*)(ws + off); off += fB;
    float* hbuf = (float*)(ws + off); off += fB;
    int* deg    = (int*)(ws + off);   off += (size_t)N * sizeof(int);
    int* cursor = (int*)(ws + off);   off += (size_t)N * sizeof(int);  // adjacent to deg
    int* rowptr = (int*)(ws + off);   off += (size_t)(N + 1) * sizeof(int);
    off = (off + 255) & ~(size_t)255;
    int* bsums  = (int*)(ws + off);   off += 512;
    int* csr    = (int*)(ws + off);   off += (size_t)E * sizeof(int);
    off = (off + 255) & ~(size_t)255;
    float* dinv = (float*)(ws + off); off += (size_t)N * sizeof(float);
    off = (off + 255) & ~(size_t)255;
    float* pooled = (float*)(ws + off); off += 64 * 128 * sizeof(float);

    // partial pooling buffer: reuse gbuf (dead after second aggregate)
    float* partial = gbuf;  // 64 * POOL_SUB * 128 floats = 1 MB << fB

    // zero deg + cursor (contiguous)
    hipMemsetAsync(deg, 0, (size_t)2 * N * sizeof(int), stream);

    int eb = (E + 255) / 256;
    count_deg_kernel<<<eb, 256, 0, stream>>>(dstIdx, E, deg);

    int nb = (N + 1023) / 1024;  // 49 for N=50000 (<=64 required by scan_pass2)
    scan_pass1<<<nb, 256, 0, stream>>>(deg, N, rowptr, bsums);
    scan_pass2<<<1, 64, 0, stream>>>(bsums, nb);
    scan_pass3<<<nb, 256, 0, stream>>>(rowptr, bsums, N, nb);
    dinv_kernel<<<(N + 255) / 256, 256, 0, stream>>>(deg, dinv, N);
    fill_csr_kernel<<<eb, 256, 0, stream>>>(srcIdx, dstIdx, E, rowptr, cursor, csr);

    int gb = (N + 63) / 64;
    int ab = (N + 3) / 4;  // 4 waves (nodes) per 256-thread block

    // layer 1
    gemm_scale_kernel<<<gb, 256, 0, stream>>>(x, W1, dinv, gbuf, N);
    aggregate_kernel<<<ab, 256, 0, stream>>>(gbuf, rowptr, csr, dinv, b1, hbuf, N);
    // layer 2
    gemm_scale_kernel<<<gb, 256, 0, stream>>>(hbuf, W2, dinv, gbuf, N);
    aggregate_kernel<<<ab, 256, 0, stream>>>(gbuf, rowptr, csr, dinv, b2, hbuf, N);

    // pooling + LSTM + heads (partial buffer reuses gbuf, dead by now)
    pool_partial_kernel<<<64 * POOL_SUB, 128, 0, stream>>>(hbuf, batch, N, partial);
    pool_finish_kernel<<<64, 128, 0, stream>>>(partial, batch, N, pooled);
    lstm_head_kernel<<<64, 256, 0, stream>>>(pooled, W_ih, b_ih, b_hh, Wm, bm, Wv, bv, out);
}

// Round 5
// 280.900 us; speedup vs baseline: 1.7754x; 1.1109x over previous
//
#include <hip/hip_runtime.h>
#include <hip/hip_bf16.h>
#include <math.h>

// ---------------------------------------------------------------------------
// GCN(2 layers, fused norm) -> mean-pool -> LSTM step (h0=c0=0) -> heads
// ---------------------------------------------------------------------------

#define POOL_SUB 32
#define GB_BM 64
#define GB_BK 32

__global__ void count_deg_kernel(const int* __restrict__ dst, int E, int* __restrict__ deg) {
    int e = blockIdx.x * blockDim.x + threadIdx.x;
    if (e < E) atomicAdd(&deg[dst[e]], 1);
}

// block scans 1024 elements (256 threads x 4)
__global__ void scan_pass1(const int* __restrict__ deg, int n,
                           int* __restrict__ rowptr, int* __restrict__ bsums) {
    __shared__ int s[256];
    int tid = threadIdx.x;
    int base = blockIdx.x * 1024;
    int v[4];
    int mysum = 0;
#pragma unroll
    for (int j = 0; j < 4; ++j) {
        int idx = base + tid * 4 + j;
        v[j] = (idx < n) ? deg[idx] : 0;
        mysum += v[j];
    }
    s[tid] = mysum;
    __syncthreads();
    for (int off = 1; off < 256; off <<= 1) {
        int t = (tid >= off) ? s[tid - off] : 0;
        __syncthreads();
        s[tid] += t;
        __syncthreads();
    }
    int excl = s[tid] - mysum;
#pragma unroll
    for (int j = 0; j < 4; ++j) {
        int idx = base + tid * 4 + j;
        if (idx < n) rowptr[idx] = excl;
        excl += v[j];
    }
    if (tid == 255) bsums[blockIdx.x] = s[255];
}

// scan up to 64 block sums (nb <= 64), exclusive; bsums[nb] = total
__global__ void scan_pass2(int* bsums, int nb) {
    __shared__ int s[64];
    int tid = threadIdx.x;
    int v = (tid < nb) ? bsums[tid] : 0;
    s[tid] = v;
    __syncthreads();
    for (int off = 1; off < 64; off <<= 1) {
        int t = (tid >= off) ? s[tid - off] : 0;
        __syncthreads();
        s[tid] += t;
        __syncthreads();
    }
    if (tid < nb) bsums[tid] = s[tid] - v;
    if (tid == 63) bsums[nb] = s[63];
}

__global__ void scan_pass3(int* __restrict__ rowptr, const int* __restrict__ bsums, int n, int nb) {
    int tid = threadIdx.x;
    int base = blockIdx.x * 1024;
    int add = bsums[blockIdx.x];
#pragma unroll
    for (int j = 0; j < 4; ++j) {
        int idx = base + tid * 4 + j;
        if (idx < n) rowptr[idx] += add;
    }
    if (blockIdx.x == 0 && tid == 0) rowptr[n] = bsums[nb];
}

__global__ void fill_csr_kernel(const int* __restrict__ src, const int* __restrict__ dst, int E,
                                const int* __restrict__ rowptr, int* __restrict__ cursor,
                                int* __restrict__ csr) {
    int e = blockIdx.x * blockDim.x + threadIdx.x;
    if (e < E) {
        int d = dst[e];
        int pos = rowptr[d] + atomicAdd(&cursor[d], 1);
        csr[pos] = src[e];
    }
}

__global__ void dinv_kernel(const int* __restrict__ deg, float* __restrict__ dinv, int n) {
    int i = blockIdx.x * blockDim.x + threadIdx.x;
    if (i < n) dinv[i] = rsqrtf((float)deg[i] + 1.0f);  // +1 self loop; always > 0
}

// out[r][c] = dinv[r] * sum_k A[r][k]*W[k][c]   (A: n x 128, W: 128 x 128 row-major)
// 128 threads; BM=64 x BN=128; K chunked by 32; 8x8 per-thread tile (split
// rows ty*4/+32, cols tx*4/+64 -> <=2-way LDS bank aliasing). LDS 24 KB.
#define FMA4(ACC, XS, WV) { ACC.x += (XS) * WV.x; ACC.y += (XS) * WV.y; \
                            ACC.z += (XS) * WV.z; ACC.w += (XS) * WV.w; }
__global__ __launch_bounds__(128) void gemm_scale_kernel(const float* __restrict__ A,
                                                         const float* __restrict__ W,
                                                         const float* __restrict__ dinv,
                                                         float* __restrict__ out, int n) {
    __shared__ __align__(16) float Ws[GB_BK][128];    // 16 KB
    __shared__ __align__(16) float Xt[GB_BK][GB_BM];  // 8 KB, k-major
    int tid = threadIdx.x;
    int rowbase = blockIdx.x * GB_BM;
    int nrow = n - rowbase; if (nrow > GB_BM) nrow = GB_BM;
    int tx = tid & 15;   // 16 col groups
    int ty = tid >> 4;   // 8 row groups

    float4 acc[2][2][4];
#pragma unroll
    for (int i = 0; i < 2; ++i)
#pragma unroll
        for (int j = 0; j < 2; ++j)
#pragma unroll
            for (int r = 0; r < 4; ++r) acc[i][j][r] = make_float4(0.f, 0.f, 0.f, 0.f);

    const float4* W4 = (const float4*)W;
    const float4* A4 = (const float4*)(A + (size_t)rowbase * 128);

    for (int kb = 0; kb < 128; kb += GB_BK) {
        // stage W[kb..kb+31][0..127] (coalesced, b128 LDS writes)
#pragma unroll
        for (int p = 0; p < 8; ++p) {
            int idx = p * 128 + tid;            // 0..1023
            int kk = idx >> 5, c4 = idx & 31;
            ((float4*)&Ws[kk][0])[c4] = W4[(size_t)(kb + kk) * 32 + c4];
        }
        // stage Xt[k][r] transposed (scalar writes, 2-way bank at worst)
#pragma unroll
        for (int p = 0; p < 4; ++p) {
            int idx = p * 128 + tid;            // 0..511
            int r = idx & 63, kg = idx >> 6;    // kg 0..7
            float4 v = make_float4(0.f, 0.f, 0.f, 0.f);
            if (r < nrow) v = A4[(size_t)r * 32 + (kb >> 2) + kg];
            Xt[kg * 4 + 0][r] = v.x;
            Xt[kg * 4 + 1][r] = v.y;
            Xt[kg * 4 + 2][r] = v.z;
            Xt[kg * 4 + 3][r] = v.w;
        }
        __syncthreads();
#pragma unroll 4
        for (int kk = 0; kk < GB_BK; ++kk) {
            float4 xa = *(const float4*)&Xt[kk][ty * 4];
            float4 xb = *(const float4*)&Xt[kk][ty * 4 + 32];
            float4 wa = *(const float4*)&Ws[kk][tx * 4];
            float4 wb = *(const float4*)&Ws[kk][tx * 4 + 64];
            FMA4(acc[0][0][0], xa.x, wa); FMA4(acc[0][1][0], xa.x, wb);
            FMA4(acc[0][0][1], xa.y, wa); FMA4(acc[0][1][1], xa.y, wb);
            FMA4(acc[0][0][2], xa.z, wa); FMA4(acc[0][1][2], xa.z, wb);
            FMA4(acc[0][0][3], xa.w, wa); FMA4(acc[0][1][3], xa.w, wb);
            FMA4(acc[1][0][0], xb.x, wa); FMA4(acc[1][1][0], xb.x, wb);
            FMA4(acc[1][0][1], xb.y, wa); FMA4(acc[1][1][1], xb.y, wb);
            FMA4(acc[1][0][2], xb.z, wa); FMA4(acc[1][1][2], xb.z, wb);
            FMA4(acc[1][0][3], xb.w, wa); FMA4(acc[1][1][3], xb.w, wb);
        }
        __syncthreads();
    }

#pragma unroll
    for (int rh = 0; rh < 2; ++rh)
#pragma unroll
        for (int r = 0; r < 4; ++r) {
            int row = rowbase + ty * 4 + r + rh * 32;
            if (row < n) {
                float s = dinv[row];
                float4 oa = acc[rh][0][r], ob = acc[rh][1][r];
                oa.x *= s; oa.y *= s; oa.z *= s; oa.w *= s;
                ob.x *= s; ob.y *= s; ob.z *= s; ob.w *= s;
                *(float4*)&out[(size_t)row * 128 + tx * 4] = oa;
                *(float4*)&out[(size_t)row * 128 + tx * 4 + 64] = ob;
            }
        }
}

// out[i] = relu(dinv[i] * (sum_{e in in(i)} g[src_e] + g[i]) + bias)
// one wave (64 lanes) per node, lane owns float2 of the 128 features
__global__ __launch_bounds__(256) void aggregate_kernel(const float* __restrict__ g,
                                                        const int* __restrict__ rowptr,
                                                        const int* __restrict__ csr,
                                                        const float* __restrict__ dinv,
                                                        const float* __restrict__ bias,
                                                        float* __restrict__ out, int n) {
    int lane = threadIdx.x & 63;
    int node = (blockIdx.x * blockDim.x + threadIdx.x) >> 6;
    if (node >= n) return;
    int beg = rowptr[node], end = rowptr[node + 1];
    const float2* __restrict__ g2 = (const float2*)g;
    float2 acc = g2[(size_t)node * 64 + lane];  // self-loop term
    int e = beg;
    for (; e + 4 <= end; e += 4) {
        int s0 = csr[e + 0], s1 = csr[e + 1], s2 = csr[e + 2], s3 = csr[e + 3];
        float2 v0 = g2[(size_t)s0 * 64 + lane];
        float2 v1 = g2[(size_t)s1 * 64 + lane];
        float2 v2 = g2[(size_t)s2 * 64 + lane];
        float2 v3 = g2[(size_t)s3 * 64 + lane];
        acc.x += v0.x + v1.x + v2.x + v3.x;
        acc.y += v0.y + v1.y + v2.y + v3.y;
    }
    for (; e < end; ++e) {
        int s0 = csr[e];
        float2 v0 = g2[(size_t)s0 * 64 + lane];
        acc.x += v0.x;
        acc.y += v0.y;
    }
    float dv = dinv[node];
    float2 b = ((const float2*)bias)[lane];
    float2 r;
    r.x = fmaxf(dv * acc.x + b.x, 0.f);
    r.y = fmaxf(dv * acc.y + b.y, 0.f);
    ((float2*)out)[(size_t)node * 64 + lane] = r;
}

// stage 1: 64 graphs x POOL_SUB sub-blocks; each sub-block sums a fixed slice
// of the graph's row range (batch sorted -> binary search). Deterministic.
__global__ __launch_bounds__(128) void pool_partial_kernel(const float* __restrict__ h,
                                                           const int* __restrict__ batch, int n,
                                                           float* __restrict__ partial) {
    int g = blockIdx.x / POOL_SUB;
    int sub = blockIdx.x % POOL_SUB;
    int tid = threadIdx.x;  // 128 threads, one feature each
    int lo = 0, hi = n;
    while (lo < hi) { int mid = (lo + hi) >> 1; if (batch[mid] < g) lo = mid + 1; else hi = mid; }
    int start = lo;
    hi = n;
    while (lo < hi) { int mid = (lo + hi) >> 1; if (batch[mid] < g + 1) lo = mid + 1; else hi = mid; }
    int end = lo;
    int len = end - start;
    int b0 = start + (int)((long long)len * sub / POOL_SUB);
    int b1 = start + (int)((long long)len * (sub + 1) / POOL_SUB);
    float acc = 0.f;
    int i = b0;
    for (; i + 4 <= b1; i += 4) {
        float v0 = h[(size_t)(i + 0) * 128 + tid];
        float v1 = h[(size_t)(i + 1) * 128 + tid];
        float v2 = h[(size_t)(i + 2) * 128 + tid];
        float v3 = h[(size_t)(i + 3) * 128 + tid];
        acc += v0 + v1 + v2 + v3;
    }
    for (; i < b1; ++i) acc += h[(size_t)i * 128 + tid];
    partial[(size_t)blockIdx.x * 128 + tid] = acc;
}

// stage 2: 64 blocks; sum POOL_SUB partials, divide by count
__global__ __launch_bounds__(128) void pool_finish_kernel(const float* __restrict__ partial,
                                                          const int* __restrict__ batch, int n,
                                                          float* __restrict__ pooled) {
    int g = blockIdx.x;
    int tid = threadIdx.x;
    int lo = 0, hi = n;
    while (lo < hi) { int mid = (lo + hi) >> 1; if (batch[mid] < g) lo = mid + 1; else hi = mid; }
    int start = lo;
    hi = n;
    while (lo < hi) { int mid = (lo + hi) >> 1; if (batch[mid] < g + 1) lo = mid + 1; else hi = mid; }
    int end = lo;
    float acc = 0.f;
#pragma unroll
    for (int s = 0; s < POOL_SUB; ++s)
        acc += partial[(size_t)(g * POOL_SUB + s) * 128 + tid];
    pooled[g * 128 + tid] = acc / fmaxf((float)(end - start), 1.0f);
}

// one block (256 threads) per graph; thread t owns hidden unit t.
// gates order i,f,g,o ; f is dead (c0=0). W_hh term dead (h0=0).
__global__ __launch_bounds__(256) void lstm_head_kernel(const float* __restrict__ pooled,
                                                        const float* __restrict__ W_ih,
                                                        const float* __restrict__ b_ih,
                                                        const float* __restrict__ b_hh,
                                                        const float* __restrict__ Wm,
                                                        const float* __restrict__ bm,
                                                        const float* __restrict__ Wv,
                                                        const float* __restrict__ bv,
                                                        float* __restrict__ out) {
    __shared__ __align__(16) float p[128];
    __shared__ float redm[256];
    __shared__ float redv[256];
    int gph = blockIdx.x;
    int tid = threadIdx.x;
    if (tid < 128) p[tid] = pooled[gph * 128 + tid];
    __syncthreads();
    float gi = b_ih[tid] + b_hh[tid];
    float gg = b_ih[512 + tid] + b_hh[512 + tid];
    float go = b_ih[768 + tid] + b_hh[768 + tid];
    const float4* wi = (const float4*)(W_ih + (size_t)tid * 128);
    const float4* wg = (const float4*)(W_ih + (size_t)(512 + tid) * 128);
    const float4* wo = (const float4*)(W_ih + (size_t)(768 + tid) * 128);
    const float4* p4 = (const float4*)p;
#pragma unroll 8
    for (int k = 0; k < 32; ++k) {
        float4 xv = p4[k];
        float4 a = wi[k], bq = wg[k], cq = wo[k];
        gi += xv.x * a.x + xv.y * a.y + xv.z * a.z + xv.w * a.w;
        gg += xv.x * bq.x + xv.y * bq.y + xv.z * bq.z + xv.w * bq.w;
        go += xv.x * cq.x + xv.y * cq.y + xv.z * cq.z + xv.w * cq.w;
    }
    float iv = 1.f / (1.f + expf(-gi));
    float cv = iv * tanhf(gg);
    float ov = 1.f / (1.f + expf(-go));
    float hT = ov * tanhf(cv);
    redm[tid] = hT * Wm[tid];
    redv[tid] = hT * Wv[tid];
    __syncthreads();
    for (int s = 128; s > 0; s >>= 1) {
        if (tid < s) { redm[tid] += redm[tid + s]; redv[tid] += redv[tid + s]; }
        __syncthreads();
    }
    if (tid == 0) {
        out[gph] = redm[0] + bm[0];
        float xv = redv[0] + bv[0];
        out[64 + gph] = fmaxf(xv, 0.f) + log1pf(expf(-fabsf(xv)));  // stable softplus
    }
}

extern "C" void kernel_launch(void* const* d_in, const int* in_sizes, int n_in,
                              void* d_out, int out_size, void* d_ws, size_t ws_size,
                              hipStream_t stream) {
    const float* x     = (const float*)d_in[0];
    const int*   edge  = (const int*)d_in[1];
    const int*   batch = (const int*)d_in[2];
    const float* W1    = (const float*)d_in[3];
    const float* b1    = (const float*)d_in[4];
    const float* W2    = (const float*)d_in[5];
    const float* b2    = (const float*)d_in[6];
    const float* W_ih  = (const float*)d_in[7];
    /* d_in[8] = W_hh: dead (h0 = 0) */
    const float* b_ih  = (const float*)d_in[9];
    const float* b_hh  = (const float*)d_in[10];
    const float* Wm    = (const float*)d_in[11];
    const float* bm    = (const float*)d_in[12];
    const float* Wv    = (const float*)d_in[13];
    const float* bv    = (const float*)d_in[14];
    float* out = (float*)d_out;

    const int N = in_sizes[0] / 128;
    const int E = in_sizes[1] / 2;
    const int* srcIdx = edge;      // edge_index[0]
    const int* dstIdx = edge + E;  // edge_index[1]

    char* ws = (char*)d_ws;
    size_t off = 0;
    const size_t fB = (size_t)N * 128 * sizeof(float);
    float* gbuf = (float*)(ws + off); off += fB;
    float* hbuf = (float*)(ws + off); off += fB;
    int* deg    = (int*)(ws + off);   off += (size_t)N * sizeof(int);
    int* cursor = (int*)(ws + off);   off += (size_t)N * sizeof(int);  // adjacent to deg
    int* rowptr = (int*)(ws + off);   off += (size_t)(N + 1) * sizeof(int);
    off = (off + 255) & ~(size_t)255;
    int* bsums  = (int*)(ws + off);   off += 512;
    int* csr    = (int*)(ws + off);   off += (size_t)E * sizeof(int);
    off = (off + 255) & ~(size_t)255;
    float* dinv = (float*)(ws + off); off += (size_t)N * sizeof(float);
    off = (off + 255) & ~(size_t)255;
    float* pooled = (float*)(ws + off); off += 64 * 128 * sizeof(float);

    // partial pooling buffer: reuse gbuf (dead after second aggregate)
    float* partial = gbuf;  // 64 * POOL_SUB * 128 floats = 1 MB << fB

    // zero deg + cursor (contiguous)
    hipMemsetAsync(deg, 0, (size_t)2 * N * sizeof(int), stream);

    int eb = (E + 255) / 256;
    count_deg_kernel<<<eb, 256, 0, stream>>>(dstIdx, E, deg);

    int nb = (N + 1023) / 1024;  // 49 for N=50000 (<=64 required by scan_pass2)
    scan_pass1<<<nb, 256, 0, stream>>>(deg, N, rowptr, bsums);
    scan_pass2<<<1, 64, 0, stream>>>(bsums, nb);
    scan_pass3<<<nb, 256, 0, stream>>>(rowptr, bsums, N, nb);
    dinv_kernel<<<(N + 255) / 256, 256, 0, stream>>>(deg, dinv, N);
    fill_csr_kernel<<<eb, 256, 0, stream>>>(srcIdx, dstIdx, E, rowptr, cursor, csr);

    int gb = (N + GB_BM - 1) / GB_BM;  // 782
    int ab = (N + 3) / 4;              // 4 waves (nodes) per 256-thread block

    // layer 1
    gemm_scale_kernel<<<gb, 128, 0, stream>>>(x, W1, dinv, gbuf, N);
    aggregate_kernel<<<ab, 256, 0, stream>>>(gbuf, rowptr, csr, dinv, b1, hbuf, N);
    // layer 2
    gemm_scale_kernel<<<gb, 128, 0, stream>>>(hbuf, W2, dinv, gbuf, N);
    aggregate_kernel<<<ab, 256, 0, stream>>>(gbuf, rowptr, csr, dinv, b2, hbuf, N);

    // pooling + LSTM + heads (partial buffer reuses gbuf, dead by now)
    pool_partial_kernel<<<64 * POOL_SUB, 128, 0, stream>>>(hbuf, batch, N, partial);
    pool_finish_kernel<<<64, 128, 0, stream>>>(partial, batch, N, pooled);
    lstm_head_kernel<<<64, 256, 0, stream>>>(pooled, W_ih, b_ih, b_hh, Wm, bm, Wv, bv, out);
}

// Round 6
// 257.943 us; speedup vs baseline: 1.9334x; 1.0890x over previous
//
#include <hip/hip_runtime.h>
#include <hip/hip_bf16.h>
#include <math.h>

// ---------------------------------------------------------------------------
// GCN(2 layers, fused norm) -> mean-pool -> LSTM step (h0=c0=0) -> heads
// Gather buffer (GEMM output) in bf16; all accumulation f32.
// ---------------------------------------------------------------------------

#define POOL_SUB 32
#define GB_BM 64
#define GB_BK 32

static __device__ __forceinline__ unsigned short f2bf(float f) {
    union { float f; unsigned int u; } v; v.f = f;
    unsigned int u = v.u;
    unsigned int r = u + 0x7FFFu + ((u >> 16) & 1u);  // RNE
    return (unsigned short)(r >> 16);
}
static __device__ __forceinline__ unsigned int pack2bf(float lo, float hi) {
    return (unsigned int)f2bf(lo) | ((unsigned int)f2bf(hi) << 16);
}
static __device__ __forceinline__ float bflo(unsigned int v) {
    union { unsigned int u; float f; } w; w.u = v << 16; return w.f;
}
static __device__ __forceinline__ float bfhi(unsigned int v) {
    union { unsigned int u; float f; } w; w.u = v & 0xFFFF0000u; return w.f;
}

__global__ void count_deg_kernel(const int* __restrict__ dst, int E, int* __restrict__ deg) {
    int e = blockIdx.x * blockDim.x + threadIdx.x;
    if (e < E) atomicAdd(&deg[dst[e]], 1);
}

// block scans 1024 elements (256 threads x 4)
__global__ void scan_pass1(const int* __restrict__ deg, int n,
                           int* __restrict__ rowptr, int* __restrict__ bsums) {
    __shared__ int s[256];
    int tid = threadIdx.x;
    int base = blockIdx.x * 1024;
    int v[4];
    int mysum = 0;
#pragma unroll
    for (int j = 0; j < 4; ++j) {
        int idx = base + tid * 4 + j;
        v[j] = (idx < n) ? deg[idx] : 0;
        mysum += v[j];
    }
    s[tid] = mysum;
    __syncthreads();
    for (int off = 1; off < 256; off <<= 1) {
        int t = (tid >= off) ? s[tid - off] : 0;
        __syncthreads();
        s[tid] += t;
        __syncthreads();
    }
    int excl = s[tid] - mysum;
#pragma unroll
    for (int j = 0; j < 4; ++j) {
        int idx = base + tid * 4 + j;
        if (idx < n) rowptr[idx] = excl;
        excl += v[j];
    }
    if (tid == 255) bsums[blockIdx.x] = s[255];
}

// scan up to 64 block sums (nb <= 64), exclusive; bsums[nb] = total
__global__ void scan_pass2(int* bsums, int nb) {
    __shared__ int s[64];
    int tid = threadIdx.x;
    int v = (tid < nb) ? bsums[tid] : 0;
    s[tid] = v;
    __syncthreads();
    for (int off = 1; off < 64; off <<= 1) {
        int t = (tid >= off) ? s[tid - off] : 0;
        __syncthreads();
        s[tid] += t;
        __syncthreads();
    }
    if (tid < nb) bsums[tid] = s[tid] - v;
    if (tid == 63) bsums[nb] = s[63];
}

__global__ void scan_pass3(int* __restrict__ rowptr, const int* __restrict__ bsums, int n, int nb) {
    int tid = threadIdx.x;
    int base = blockIdx.x * 1024;
    int add = bsums[blockIdx.x];
#pragma unroll
    for (int j = 0; j < 4; ++j) {
        int idx = base + tid * 4 + j;
        if (idx < n) rowptr[idx] += add;
    }
    if (blockIdx.x == 0 && tid == 0) rowptr[n] = bsums[nb];
}

__global__ void fill_csr_kernel(const int* __restrict__ src, const int* __restrict__ dst, int E,
                                const int* __restrict__ rowptr, int* __restrict__ cursor,
                                int* __restrict__ csr) {
    int e = blockIdx.x * blockDim.x + threadIdx.x;
    if (e < E) {
        int d = dst[e];
        int pos = rowptr[d] + atomicAdd(&cursor[d], 1);
        csr[pos] = src[e];
    }
}

__global__ void dinv_kernel(const int* __restrict__ deg, float* __restrict__ dinv, int n) {
    int i = blockIdx.x * blockDim.x + threadIdx.x;
    if (i < n) dinv[i] = rsqrtf((float)deg[i] + 1.0f);  // +1 self loop; always > 0
}

// out[r][c] = bf16( dinv[r] * sum_k A[r][k]*W[k][c] )  (A: n x 128 f32, W: 128x128 f32)
// 128 threads; BM=64 x BN=128; K chunked by 32; 8x8 per-thread tile.
#define FMA4(ACC, XS, WV) { ACC.x += (XS) * WV.x; ACC.y += (XS) * WV.y; \
                            ACC.z += (XS) * WV.z; ACC.w += (XS) * WV.w; }
__global__ __launch_bounds__(128) void gemm_scale_kernel(const float* __restrict__ A,
                                                         const float* __restrict__ W,
                                                         const float* __restrict__ dinv,
                                                         unsigned int* __restrict__ out,  // bf16x2
                                                         int n) {
    __shared__ __align__(16) float Ws[GB_BK][128];    // 16 KB
    __shared__ __align__(16) float Xt[GB_BK][GB_BM];  // 8 KB, k-major
    int tid = threadIdx.x;
    int rowbase = blockIdx.x * GB_BM;
    int nrow = n - rowbase; if (nrow > GB_BM) nrow = GB_BM;
    int tx = tid & 15;   // 16 col groups
    int ty = tid >> 4;   // 8 row groups

    float4 acc[2][2][4];
#pragma unroll
    for (int i = 0; i < 2; ++i)
#pragma unroll
        for (int j = 0; j < 2; ++j)
#pragma unroll
            for (int r = 0; r < 4; ++r) acc[i][j][r] = make_float4(0.f, 0.f, 0.f, 0.f);

    const float4* W4 = (const float4*)W;
    const float4* A4 = (const float4*)(A + (size_t)rowbase * 128);

    for (int kb = 0; kb < 128; kb += GB_BK) {
#pragma unroll
        for (int p = 0; p < 8; ++p) {
            int idx = p * 128 + tid;            // 0..1023
            int kk = idx >> 5, c4 = idx & 31;
            ((float4*)&Ws[kk][0])[c4] = W4[(size_t)(kb + kk) * 32 + c4];
        }
#pragma unroll
        for (int p = 0; p < 4; ++p) {
            int idx = p * 128 + tid;            // 0..511
            int r = idx & 63, kg = idx >> 6;    // kg 0..7
            float4 v = make_float4(0.f, 0.f, 0.f, 0.f);
            if (r < nrow) v = A4[(size_t)r * 32 + (kb >> 2) + kg];
            Xt[kg * 4 + 0][r] = v.x;
            Xt[kg * 4 + 1][r] = v.y;
            Xt[kg * 4 + 2][r] = v.z;
            Xt[kg * 4 + 3][r] = v.w;
        }
        __syncthreads();
#pragma unroll 4
        for (int kk = 0; kk < GB_BK; ++kk) {
            float4 xa = *(const float4*)&Xt[kk][ty * 4];
            float4 xb = *(const float4*)&Xt[kk][ty * 4 + 32];
            float4 wa = *(const float4*)&Ws[kk][tx * 4];
            float4 wb = *(const float4*)&Ws[kk][tx * 4 + 64];
            FMA4(acc[0][0][0], xa.x, wa); FMA4(acc[0][1][0], xa.x, wb);
            FMA4(acc[0][0][1], xa.y, wa); FMA4(acc[0][1][1], xa.y, wb);
            FMA4(acc[0][0][2], xa.z, wa); FMA4(acc[0][1][2], xa.z, wb);
            FMA4(acc[0][0][3], xa.w, wa); FMA4(acc[0][1][3], xa.w, wb);
            FMA4(acc[1][0][0], xb.x, wa); FMA4(acc[1][1][0], xb.x, wb);
            FMA4(acc[1][0][1], xb.y, wa); FMA4(acc[1][1][1], xb.y, wb);
            FMA4(acc[1][0][2], xb.z, wa); FMA4(acc[1][1][2], xb.z, wb);
            FMA4(acc[1][0][3], xb.w, wa); FMA4(acc[1][1][3], xb.w, wb);
        }
        __syncthreads();
    }

#pragma unroll
    for (int rh = 0; rh < 2; ++rh)
#pragma unroll
        for (int r = 0; r < 4; ++r) {
            int row = rowbase + ty * 4 + r + rh * 32;
            if (row < n) {
                float s = dinv[row];
                float4 oa = acc[rh][0][r], ob = acc[rh][1][r];
                uint2* orow = (uint2*)(out + (size_t)row * 64);  // 64 uints/row
                orow[tx]      = make_uint2(pack2bf(oa.x * s, oa.y * s),
                                           pack2bf(oa.z * s, oa.w * s));
                orow[tx + 16] = make_uint2(pack2bf(ob.x * s, ob.y * s),
                                           pack2bf(ob.z * s, ob.w * s));
            }
        }
}

// out[i] = relu(dinv[i] * (sum_{e in in(i)} g[src_e] + g[i]) + bias)   (g in bf16)
// one wave (64 lanes) per node, lane owns 2 features (one packed uint)
__global__ __launch_bounds__(256) void aggregate_kernel(const unsigned int* __restrict__ g,
                                                        const int* __restrict__ rowptr,
                                                        const int* __restrict__ csr,
                                                        const float* __restrict__ dinv,
                                                        const float* __restrict__ bias,
                                                        float* __restrict__ out, int n) {
    int lane = threadIdx.x & 63;
    int node = (blockIdx.x * blockDim.x + threadIdx.x) >> 6;
    if (node >= n) return;
    int beg = rowptr[node], end = rowptr[node + 1];
    unsigned int sv = g[(size_t)node * 64 + lane];  // self-loop term
    float ax = bflo(sv), ay = bfhi(sv);
    int e = beg;
    for (; e + 4 <= end; e += 4) {
        int s0 = csr[e + 0], s1 = csr[e + 1], s2 = csr[e + 2], s3 = csr[e + 3];
        unsigned int v0 = g[(size_t)s0 * 64 + lane];
        unsigned int v1 = g[(size_t)s1 * 64 + lane];
        unsigned int v2 = g[(size_t)s2 * 64 + lane];
        unsigned int v3 = g[(size_t)s3 * 64 + lane];
        ax += bflo(v0) + bflo(v1) + bflo(v2) + bflo(v3);
        ay += bfhi(v0) + bfhi(v1) + bfhi(v2) + bfhi(v3);
    }
    for (; e < end; ++e) {
        unsigned int v0 = g[(size_t)csr[e] * 64 + lane];
        ax += bflo(v0);
        ay += bfhi(v0);
    }
    float dv = dinv[node];
    float2 b = ((const float2*)bias)[lane];
    float2 r;
    r.x = fmaxf(dv * ax + b.x, 0.f);
    r.y = fmaxf(dv * ay + b.y, 0.f);
    ((float2*)out)[(size_t)node * 64 + lane] = r;
}

// stage 1: 64 graphs x POOL_SUB sub-blocks; each sub-block sums a fixed slice
// of the graph's row range (batch sorted -> binary search). Deterministic.
__global__ __launch_bounds__(128) void pool_partial_kernel(const float* __restrict__ h,
                                                           const int* __restrict__ batch, int n,
                                                           float* __restrict__ partial) {
    int g = blockIdx.x / POOL_SUB;
    int sub = blockIdx.x % POOL_SUB;
    int tid = threadIdx.x;  // 128 threads, one feature each
    int lo = 0, hi = n;
    while (lo < hi) { int mid = (lo + hi) >> 1; if (batch[mid] < g) lo = mid + 1; else hi = mid; }
    int start = lo;
    hi = n;
    while (lo < hi) { int mid = (lo + hi) >> 1; if (batch[mid] < g + 1) lo = mid + 1; else hi = mid; }
    int end = lo;
    int len = end - start;
    int b0 = start + (int)((long long)len * sub / POOL_SUB);
    int b1 = start + (int)((long long)len * (sub + 1) / POOL_SUB);
    float acc = 0.f;
    int i = b0;
    for (; i + 4 <= b1; i += 4) {
        float v0 = h[(size_t)(i + 0) * 128 + tid];
        float v1 = h[(size_t)(i + 1) * 128 + tid];
        float v2 = h[(size_t)(i + 2) * 128 + tid];
        float v3 = h[(size_t)(i + 3) * 128 + tid];
        acc += v0 + v1 + v2 + v3;
    }
    for (; i < b1; ++i) acc += h[(size_t)i * 128 + tid];
    partial[(size_t)blockIdx.x * 128 + tid] = acc;
}

// stage 2: 64 blocks; sum POOL_SUB partials, divide by count
__global__ __launch_bounds__(128) void pool_finish_kernel(const float* __restrict__ partial,
                                                          const int* __restrict__ batch, int n,
                                                          float* __restrict__ pooled) {
    int g = blockIdx.x;
    int tid = threadIdx.x;
    int lo = 0, hi = n;
    while (lo < hi) { int mid = (lo + hi) >> 1; if (batch[mid] < g) lo = mid + 1; else hi = mid; }
    int start = lo;
    hi = n;
    while (lo < hi) { int mid = (lo + hi) >> 1; if (batch[mid] < g + 1) lo = mid + 1; else hi = mid; }
    int end = lo;
    float acc = 0.f;
#pragma unroll
    for (int s = 0; s < POOL_SUB; ++s)
        acc += partial[(size_t)(g * POOL_SUB + s) * 128 + tid];
    pooled[g * 128 + tid] = acc / fmaxf((float)(end - start), 1.0f);
}

// one block (256 threads) per graph; thread t owns hidden unit t.
// gates order i,f,g,o ; f is dead (c0=0). W_hh term dead (h0=0).
__global__ __launch_bounds__(256) void lstm_head_kernel(const float* __restrict__ pooled,
                                                        const float* __restrict__ W_ih,
                                                        const float* __restrict__ b_ih,
                                                        const float* __restrict__ b_hh,
                                                        const float* __restrict__ Wm,
                                                        const float* __restrict__ bm,
                                                        const float* __restrict__ Wv,
                                                        const float* __restrict__ bv,
                                                        float* __restrict__ out) {
    __shared__ __align__(16) float p[128];
    __shared__ float redm[256];
    __shared__ float redv[256];
    int gph = blockIdx.x;
    int tid = threadIdx.x;
    if (tid < 128) p[tid] = pooled[gph * 128 + tid];
    __syncthreads();
    float gi = b_ih[tid] + b_hh[tid];
    float gg = b_ih[512 + tid] + b_hh[512 + tid];
    float go = b_ih[768 + tid] + b_hh[768 + tid];
    const float4* wi = (const float4*)(W_ih + (size_t)tid * 128);
    const float4* wg = (const float4*)(W_ih + (size_t)(512 + tid) * 128);
    const float4* wo = (const float4*)(W_ih + (size_t)(768 + tid) * 128);
    const float4* p4 = (const float4*)p;
#pragma unroll 8
    for (int k = 0; k < 32; ++k) {
        float4 xv = p4[k];
        float4 a = wi[k], bq = wg[k], cq = wo[k];
        gi += xv.x * a.x + xv.y * a.y + xv.z * a.z + xv.w * a.w;
        gg += xv.x * bq.x + xv.y * bq.y + xv.z * bq.z + xv.w * bq.w;
        go += xv.x * cq.x + xv.y * cq.y + xv.z * cq.z + xv.w * cq.w;
    }
    float iv = 1.f / (1.f + expf(-gi));
    float cv = iv * tanhf(gg);
    float ov = 1.f / (1.f + expf(-go));
    float hT = ov * tanhf(cv);
    redm[tid] = hT * Wm[tid];
    redv[tid] = hT * Wv[tid];
    __syncthreads();
    for (int s = 128; s > 0; s >>= 1) {
        if (tid < s) { redm[tid] += redm[tid + s]; redv[tid] += redv[tid + s]; }
        __syncthreads();
    }
    if (tid == 0) {
        out[gph] = redm[0] + bm[0];
        float xv = redv[0] + bv[0];
        out[64 + gph] = fmaxf(xv, 0.f) + log1pf(expf(-fabsf(xv)));  // stable softplus
    }
}

extern "C" void kernel_launch(void* const* d_in, const int* in_sizes, int n_in,
                              void* d_out, int out_size, void* d_ws, size_t ws_size,
                              hipStream_t stream) {
    const float* x     = (const float*)d_in[0];
    const int*   edge  = (const int*)d_in[1];
    const int*   batch = (const int*)d_in[2];
    const float* W1    = (const float*)d_in[3];
    const float* b1    = (const float*)d_in[4];
    const float* W2    = (const float*)d_in[5];
    const float* b2    = (const float*)d_in[6];
    const float* W_ih  = (const float*)d_in[7];
    /* d_in[8] = W_hh: dead (h0 = 0) */
    const float* b_ih  = (const float*)d_in[9];
    const float* b_hh  = (const float*)d_in[10];
    const float* Wm    = (const float*)d_in[11];
    const float* bm    = (const float*)d_in[12];
    const float* Wv    = (const float*)d_in[13];
    const float* bv    = (const float*)d_in[14];
    float* out = (float*)d_out;

    const int N = in_sizes[0] / 128;
    const int E = in_sizes[1] / 2;
    const int* srcIdx = edge;      // edge_index[0]
    const int* dstIdx = edge + E;  // edge_index[1]

    char* ws = (char*)d_ws;
    size_t off = 0;
    const size_t fB = (size_t)N * 128 * sizeof(float);
    const size_t gB = (size_t)N * 64 * sizeof(unsigned int);  // bf16 gather buf
    unsigned int* gbuf = (unsigned int*)(ws + off); off += gB;
    float* hbuf = (float*)(ws + off); off += fB;
    int* deg    = (int*)(ws + off);   off += (size_t)N * sizeof(int);
    int* cursor = (int*)(ws + off);   off += (size_t)N * sizeof(int);  // adjacent to deg
    int* rowptr = (int*)(ws + off);   off += (size_t)(N + 1) * sizeof(int);
    off = (off + 255) & ~(size_t)255;
    int* bsums  = (int*)(ws + off);   off += 512;
    int* csr    = (int*)(ws + off);   off += (size_t)E * sizeof(int);
    off = (off + 255) & ~(size_t)255;
    float* dinv = (float*)(ws + off); off += (size_t)N * sizeof(float);
    off = (off + 255) & ~(size_t)255;
    float* pooled = (float*)(ws + off); off += 64 * 128 * sizeof(float);
    off = (off + 255) & ~(size_t)255;
    float* partial = (float*)(ws + off); off += (size_t)64 * POOL_SUB * 128 * sizeof(float);

    // zero deg + cursor (contiguous)
    hipMemsetAsync(deg, 0, (size_t)2 * N * sizeof(int), stream);

    int eb = (E + 255) / 256;
    count_deg_kernel<<<eb, 256, 0, stream>>>(dstIdx, E, deg);

    int nb = (N + 1023) / 1024;  // 49 for N=50000 (<=64 required by scan_pass2)
    scan_pass1<<<nb, 256, 0, stream>>>(deg, N, rowptr, bsums);
    scan_pass2<<<1, 64, 0, stream>>>(bsums, nb);
    scan_pass3<<<nb, 256, 0, stream>>>(rowptr, bsums, N, nb);
    dinv_kernel<<<(N + 255) / 256, 256, 0, stream>>>(deg, dinv, N);
    fill_csr_kernel<<<eb, 256, 0, stream>>>(srcIdx, dstIdx, E, rowptr, cursor, csr);

    int gb = (N + GB_BM - 1) / GB_BM;  // 782
    int ab = (N + 3) / 4;              // 4 waves (nodes) per 256-thread block

    // layer 1
    gemm_scale_kernel<<<gb, 128, 0, stream>>>(x, W1, dinv, gbuf, N);
    aggregate_kernel<<<ab, 256, 0, stream>>>(gbuf, rowptr, csr, dinv, b1, hbuf, N);
    // layer 2
    gemm_scale_kernel<<<gb, 128, 0, stream>>>(hbuf, W2, dinv, gbuf, N);
    aggregate_kernel<<<ab, 256, 0, stream>>>(gbuf, rowptr, csr, dinv, b2, hbuf, N);

    // pooling + LSTM + heads
    pool_partial_kernel<<<64 * POOL_SUB, 128, 0, stream>>>(hbuf, batch, N, partial);
    pool_finish_kernel<<<64, 128, 0, stream>>>(partial, batch, N, pooled);
    lstm_head_kernel<<<64, 256, 0, stream>>>(pooled, W_ih, b_ih, b_hh, Wm, bm, Wv, bv, out);
}

// Round 7
// 230.181 us; speedup vs baseline: 2.1666x; 1.1206x over previous
//
#include <hip/hip_runtime.h>
#include <hip/hip_bf16.h>
#include <math.h>

// ---------------------------------------------------------------------------
// GCN(2 layers, fused norm) -> mean-pool -> LSTM step (h0=c0=0) -> heads
// GEMMs via bf16 MFMA (f32 accum); gather/feature buffers bf16; reductions f32.
// ---------------------------------------------------------------------------

#define POOL_SUB 32

typedef __attribute__((ext_vector_type(8))) short bf16x8;
typedef __attribute__((ext_vector_type(4))) float f32x4;

static __device__ __forceinline__ unsigned short f2bf(float f) {
    union { float f; unsigned int u; } v; v.f = f;
    unsigned int u = v.u;
    unsigned int r = u + 0x7FFFu + ((u >> 16) & 1u);  // RNE
    return (unsigned short)(r >> 16);
}
static __device__ __forceinline__ unsigned int pack2bf(float lo, float hi) {
    return (unsigned int)f2bf(lo) | ((unsigned int)f2bf(hi) << 16);
}
static __device__ __forceinline__ float bflo(unsigned int v) {
    union { unsigned int u; float f; } w; w.u = v << 16; return w.f;
}
static __device__ __forceinline__ float bfhi(unsigned int v) {
    union { unsigned int u; float f; } w; w.u = v & 0xFFFF0000u; return w.f;
}

__global__ void count_deg_kernel(const int* __restrict__ dst, int E, int* __restrict__ deg) {
    int e = blockIdx.x * blockDim.x + threadIdx.x;
    if (e < E) atomicAdd(&deg[dst[e]], 1);
}

// block scans 1024 elements (256 threads x 4)
__global__ void scan_pass1(const int* __restrict__ deg, int n,
                           int* __restrict__ rowptr, int* __restrict__ bsums) {
    __shared__ int s[256];
    int tid = threadIdx.x;
    int base = blockIdx.x * 1024;
    int v[4];
    int mysum = 0;
#pragma unroll
    for (int j = 0; j < 4; ++j) {
        int idx = base + tid * 4 + j;
        v[j] = (idx < n) ? deg[idx] : 0;
        mysum += v[j];
    }
    s[tid] = mysum;
    __syncthreads();
    for (int off = 1; off < 256; off <<= 1) {
        int t = (tid >= off) ? s[tid - off] : 0;
        __syncthreads();
        s[tid] += t;
        __syncthreads();
    }
    int excl = s[tid] - mysum;
#pragma unroll
    for (int j = 0; j < 4; ++j) {
        int idx = base + tid * 4 + j;
        if (idx < n) rowptr[idx] = excl;
        excl += v[j];
    }
    if (tid == 255) bsums[blockIdx.x] = s[255];
}

// scan up to 64 block sums (nb <= 64), exclusive; bsums[nb] = total
__global__ void scan_pass2(int* bsums, int nb) {
    __shared__ int s[64];
    int tid = threadIdx.x;
    int v = (tid < nb) ? bsums[tid] : 0;
    s[tid] = v;
    __syncthreads();
    for (int off = 1; off < 64; off <<= 1) {
        int t = (tid >= off) ? s[tid - off] : 0;
        __syncthreads();
        s[tid] += t;
        __syncthreads();
    }
    if (tid < nb) bsums[tid] = s[tid] - v;
    if (tid == 63) bsums[nb] = s[63];
}

__global__ void scan_pass3(int* __restrict__ rowptr, const int* __restrict__ bsums, int n, int nb) {
    int tid = threadIdx.x;
    int base = blockIdx.x * 1024;
    int add = bsums[blockIdx.x];
#pragma unroll
    for (int j = 0; j < 4; ++j) {
        int idx = base + tid * 4 + j;
        if (idx < n) rowptr[idx] += add;
    }
    if (blockIdx.x == 0 && tid == 0) rowptr[n] = bsums[nb];
}

__global__ void fill_csr_kernel(const int* __restrict__ src, const int* __restrict__ dst, int E,
                                const int* __restrict__ rowptr, int* __restrict__ cursor,
                                int* __restrict__ csr) {
    int e = blockIdx.x * blockDim.x + threadIdx.x;
    if (e < E) {
        int d = dst[e];
        int pos = rowptr[d] + atomicAdd(&cursor[d], 1);
        csr[pos] = src[e];
    }
}

__global__ void dinv_kernel(const int* __restrict__ deg, float* __restrict__ dinv, int n) {
    int i = blockIdx.x * blockDim.x + threadIdx.x;
    if (i < n) dinv[i] = rsqrtf((float)deg[i] + 1.0f);  // +1 self loop; always > 0
}

// x (f32, N x 128) -> xb (bf16 packed, N x 64 uints); thread handles 4 floats
__global__ void xcvt_kernel(const float* __restrict__ x, unsigned int* __restrict__ xb, int total4) {
    int i = blockIdx.x * blockDim.x + threadIdx.x;
    if (i < total4) {
        float4 v = ((const float4*)x)[i];
        ((uint2*)xb)[i] = make_uint2(pack2bf(v.x, v.y), pack2bf(v.z, v.w));
    }
}

// W (f32 [k][n] 128x128) -> Wt (bf16 [n][k]); blocks 0-127: W1, 128-255: W2
__global__ void wcvt_kernel(const float* __restrict__ W1, const float* __restrict__ W2,
                            unsigned short* __restrict__ Wt1, unsigned short* __restrict__ Wt2) {
    int nb = blockIdx.x & 127;
    const float* Ws = (blockIdx.x < 128) ? W1 : W2;
    unsigned short* Wd = (blockIdx.x < 128) ? Wt1 : Wt2;
    int k = threadIdx.x;
    Wd[nb * 128 + k] = f2bf(Ws[(size_t)k * 128 + nb]);
}

// out[r][c] = bf16( dinv[r] * sum_k A[r][k]*W[k][c] )
// A bf16 n x 128 row-major; Wt bf16 [n][k] (transposed W). 4 waves/block,
// each wave: 16 rows x 128 cols, K=128 -> 32 mfma_f32_16x16x32_bf16.
// A/B k-interleave consistency => any fixed (lane,elem)->k bijection is safe;
// C/D layout: col = lane&15, row = (lane>>4)*4 + reg (HW-verified).
__global__ __launch_bounds__(256) void gemm_mfma_kernel(const unsigned short* __restrict__ A,
                                                        const unsigned short* __restrict__ Wt,
                                                        const float* __restrict__ dinv,
                                                        unsigned short* __restrict__ out,
                                                        int n) {
    int tid = threadIdx.x;
    int l = tid & 63;
    int wid = tid >> 6;
    int rowbase = blockIdx.x * 64 + wid * 16;
    int lc = l & 15;
    int kq = l >> 4;

    int arow = rowbase + lc; if (arow > n - 1) arow = n - 1;
    const unsigned short* Ap = A + (size_t)arow * 128 + kq * 8;
    const unsigned short* Wp = Wt + (size_t)lc * 128 + kq * 8;

    f32x4 acc[8];
#pragma unroll
    for (int c = 0; c < 8; ++c) acc[c] = (f32x4){0.f, 0.f, 0.f, 0.f};

#pragma unroll
    for (int ks = 0; ks < 4; ++ks) {
        bf16x8 a = *(const bf16x8*)(Ap + ks * 32);
#pragma unroll
        for (int c = 0; c < 8; ++c) {
            bf16x8 b = *(const bf16x8*)(Wp + c * 2048 + ks * 32);
            acc[c] = __builtin_amdgcn_mfma_f32_16x16x32_bf16(a, b, acc[c], 0, 0, 0);
        }
    }

    int r0 = kq * 4;
    float s[4];
    int orow[4];
#pragma unroll
    for (int r = 0; r < 4; ++r) {
        orow[r] = rowbase + r0 + r;
        s[r] = (orow[r] < n) ? dinv[orow[r]] : 0.f;
    }
#pragma unroll
    for (int c = 0; c < 8; ++c) {
#pragma unroll
        for (int r = 0; r < 4; ++r) {
            if (orow[r] < n)
                out[(size_t)orow[r] * 128 + c * 16 + lc] = f2bf(acc[c][r] * s[r]);
        }
    }
}

// out[i] = bf16( relu(dinv[i] * (sum_{e in in(i)} g[src_e] + g[i]) + bias) )
// g bf16 packed; one wave per node, lane owns one packed uint (2 features)
__global__ __launch_bounds__(256) void aggregate_kernel(const unsigned int* __restrict__ g,
                                                        const int* __restrict__ rowptr,
                                                        const int* __restrict__ csr,
                                                        const float* __restrict__ dinv,
                                                        const float* __restrict__ bias,
                                                        unsigned int* __restrict__ out, int n) {
    int lane = threadIdx.x & 63;
    int node = (blockIdx.x * blockDim.x + threadIdx.x) >> 6;
    if (node >= n) return;
    int beg = rowptr[node], end = rowptr[node + 1];
    unsigned int sv = g[(size_t)node * 64 + lane];  // self-loop term
    float ax = bflo(sv), ay = bfhi(sv);
    int e = beg;
    for (; e + 4 <= end; e += 4) {
        int s0 = csr[e + 0], s1 = csr[e + 1], s2 = csr[e + 2], s3 = csr[e + 3];
        unsigned int v0 = g[(size_t)s0 * 64 + lane];
        unsigned int v1 = g[(size_t)s1 * 64 + lane];
        unsigned int v2 = g[(size_t)s2 * 64 + lane];
        unsigned int v3 = g[(size_t)s3 * 64 + lane];
        ax += bflo(v0) + bflo(v1) + bflo(v2) + bflo(v3);
        ay += bfhi(v0) + bfhi(v1) + bfhi(v2) + bfhi(v3);
    }
    for (; e < end; ++e) {
        unsigned int v0 = g[(size_t)csr[e] * 64 + lane];
        ax += bflo(v0);
        ay += bfhi(v0);
    }
    float dv = dinv[node];
    float2 b = ((const float2*)bias)[lane];
    float rx = fmaxf(dv * ax + b.x, 0.f);
    float ry = fmaxf(dv * ay + b.y, 0.f);
    out[(size_t)node * 64 + lane] = pack2bf(rx, ry);
}

// stage 1: 64 graphs x POOL_SUB sub-blocks; 64 threads, 2 features each (bf16 in)
__global__ __launch_bounds__(64) void pool_partial_kernel(const unsigned int* __restrict__ h,
                                                          const int* __restrict__ batch, int n,
                                                          float* __restrict__ partial) {
    int g = blockIdx.x / POOL_SUB;
    int sub = blockIdx.x % POOL_SUB;
    int t = threadIdx.x;  // 0..63, packed pair t
    int lo = 0, hi = n;
    while (lo < hi) { int mid = (lo + hi) >> 1; if (batch[mid] < g) lo = mid + 1; else hi = mid; }
    int start = lo;
    hi = n;
    while (lo < hi) { int mid = (lo + hi) >> 1; if (batch[mid] < g + 1) lo = mid + 1; else hi = mid; }
    int end = lo;
    int len = end - start;
    int b0 = start + (int)((long long)len * sub / POOL_SUB);
    int b1 = start + (int)((long long)len * (sub + 1) / POOL_SUB);
    float ax = 0.f, ay = 0.f;
    int i = b0;
    for (; i + 4 <= b1; i += 4) {
        unsigned int v0 = h[(size_t)(i + 0) * 64 + t];
        unsigned int v1 = h[(size_t)(i + 1) * 64 + t];
        unsigned int v2 = h[(size_t)(i + 2) * 64 + t];
        unsigned int v3 = h[(size_t)(i + 3) * 64 + t];
        ax += bflo(v0) + bflo(v1) + bflo(v2) + bflo(v3);
        ay += bfhi(v0) + bfhi(v1) + bfhi(v2) + bfhi(v3);
    }
    for (; i < b1; ++i) {
        unsigned int v0 = h[(size_t)i * 64 + t];
        ax += bflo(v0);
        ay += bfhi(v0);
    }
    partial[(size_t)blockIdx.x * 128 + 2 * t]     = ax;
    partial[(size_t)blockIdx.x * 128 + 2 * t + 1] = ay;
}

// stage 2: 64 blocks; sum POOL_SUB partials, divide by count
__global__ __launch_bounds__(128) void pool_finish_kernel(const float* __restrict__ partial,
                                                          const int* __restrict__ batch, int n,
                                                          float* __restrict__ pooled) {
    int g = blockIdx.x;
    int tid = threadIdx.x;
    int lo = 0, hi = n;
    while (lo < hi) { int mid = (lo + hi) >> 1; if (batch[mid] < g) lo = mid + 1; else hi = mid; }
    int start = lo;
    hi = n;
    while (lo < hi) { int mid = (lo + hi) >> 1; if (batch[mid] < g + 1) lo = mid + 1; else hi = mid; }
    int end = lo;
    float acc = 0.f;
#pragma unroll
    for (int s = 0; s < POOL_SUB; ++s)
        acc += partial[(size_t)(g * POOL_SUB + s) * 128 + tid];
    pooled[g * 128 + tid] = acc / fmaxf((float)(end - start), 1.0f);
}

// one block (256 threads) per graph; thread t owns hidden unit t.
// gates order i,f,g,o ; f is dead (c0=0). W_hh term dead (h0=0).
__global__ __launch_bounds__(256) void lstm_head_kernel(const float* __restrict__ pooled,
                                                        const float* __restrict__ W_ih,
                                                        const float* __restrict__ b_ih,
                                                        const float* __restrict__ b_hh,
                                                        const float* __restrict__ Wm,
                                                        const float* __restrict__ bm,
                                                        const float* __restrict__ Wv,
                                                        const float* __restrict__ bv,
                                                        float* __restrict__ out) {
    __shared__ __align__(16) float p[128];
    __shared__ float redm[256];
    __shared__ float redv[256];
    int gph = blockIdx.x;
    int tid = threadIdx.x;
    if (tid < 128) p[tid] = pooled[gph * 128 + tid];
    __syncthreads();
    float gi = b_ih[tid] + b_hh[tid];
    float gg = b_ih[512 + tid] + b_hh[512 + tid];
    float go = b_ih[768 + tid] + b_hh[768 + tid];
    const float4* wi = (const float4*)(W_ih + (size_t)tid * 128);
    const float4* wg = (const float4*)(W_ih + (size_t)(512 + tid) * 128);
    const float4* wo = (const float4*)(W_ih + (size_t)(768 + tid) * 128);
    const float4* p4 = (const float4*)p;
#pragma unroll 8
    for (int k = 0; k < 32; ++k) {
        float4 xv = p4[k];
        float4 a = wi[k], bq = wg[k], cq = wo[k];
        gi += xv.x * a.x + xv.y * a.y + xv.z * a.z + xv.w * a.w;
        gg += xv.x * bq.x + xv.y * bq.y + xv.z * bq.z + xv.w * bq.w;
        go += xv.x * cq.x + xv.y * cq.y + xv.z * cq.z + xv.w * cq.w;
    }
    float iv = 1.f / (1.f + expf(-gi));
    float cv = iv * tanhf(gg);
    float ov = 1.f / (1.f + expf(-go));
    float hT = ov * tanhf(cv);
    redm[tid] = hT * Wm[tid];
    redv[tid] = hT * Wv[tid];
    __syncthreads();
    for (int s = 128; s > 0; s >>= 1) {
        if (tid < s) { redm[tid] += redm[tid + s]; redv[tid] += redv[tid + s]; }
        __syncthreads();
    }
    if (tid == 0) {
        out[gph] = redm[0] + bm[0];
        float xv = redv[0] + bv[0];
        out[64 + gph] = fmaxf(xv, 0.f) + log1pf(expf(-fabsf(xv)));  // stable softplus
    }
}

extern "C" void kernel_launch(void* const* d_in, const int* in_sizes, int n_in,
                              void* d_out, int out_size, void* d_ws, size_t ws_size,
                              hipStream_t stream) {
    const float* x     = (const float*)d_in[0];
    const int*   edge  = (const int*)d_in[1];
    const int*   batch = (const int*)d_in[2];
    const float* W1    = (const float*)d_in[3];
    const float* b1    = (const float*)d_in[4];
    const float* W2    = (const float*)d_in[5];
    const float* b2    = (const float*)d_in[6];
    const float* W_ih  = (const float*)d_in[7];
    /* d_in[8] = W_hh: dead (h0 = 0) */
    const float* b_ih  = (const float*)d_in[9];
    const float* b_hh  = (const float*)d_in[10];
    const float* Wm    = (const float*)d_in[11];
    const float* bm    = (const float*)d_in[12];
    const float* Wv    = (const float*)d_in[13];
    const float* bv    = (const float*)d_in[14];
    float* out = (float*)d_out;

    const int N = in_sizes[0] / 128;
    const int E = in_sizes[1] / 2;
    const int* srcIdx = edge;      // edge_index[0]
    const int* dstIdx = edge + E;  // edge_index[1]

    char* ws = (char*)d_ws;
    size_t off = 0;
    const size_t gB = (size_t)N * 64 * sizeof(unsigned int);  // bf16 N x 128
    unsigned int* gbuf = (unsigned int*)(ws + off); off += gB;
    unsigned int* hbuf = (unsigned int*)(ws + off); off += gB;
    unsigned int* xb   = (unsigned int*)(ws + off); off += gB;
    int* deg    = (int*)(ws + off);   off += (size_t)N * sizeof(int);
    int* cursor = (int*)(ws + off);   off += (size_t)N * sizeof(int);  // adjacent to deg
    int* rowptr = (int*)(ws + off);   off += (size_t)(N + 1) * sizeof(int);
    off = (off + 255) & ~(size_t)255;
    int* bsums  = (int*)(ws + off);   off += 512;
    int* csr    = (int*)(ws + off);   off += (size_t)E * sizeof(int);
    off = (off + 255) & ~(size_t)255;
    float* dinv = (float*)(ws + off); off += (size_t)N * sizeof(float);
    off = (off + 255) & ~(size_t)255;
    unsigned short* Wt1 = (unsigned short*)(ws + off); off += 128 * 128 * sizeof(unsigned short);
    unsigned short* Wt2 = (unsigned short*)(ws + off); off += 128 * 128 * sizeof(unsigned short);
    off = (off + 255) & ~(size_t)255;
    float* pooled = (float*)(ws + off); off += 64 * 128 * sizeof(float);
    off = (off + 255) & ~(size_t)255;
    float* partial = (float*)(ws + off); off += (size_t)64 * POOL_SUB * 128 * sizeof(float);

    // zero deg + cursor (contiguous)
    hipMemsetAsync(deg, 0, (size_t)2 * N * sizeof(int), stream);

    // input conversions (independent of graph build)
    xcvt_kernel<<<(N * 32 + 255) / 256, 256, 0, stream>>>(x, xb, N * 32);
    wcvt_kernel<<<256, 128, 0, stream>>>(W1, W2, Wt1, Wt2);

    int eb = (E + 255) / 256;
    count_deg_kernel<<<eb, 256, 0, stream>>>(dstIdx, E, deg);

    int nb = (N + 1023) / 1024;  // 49 for N=50000 (<=64 required by scan_pass2)
    scan_pass1<<<nb, 256, 0, stream>>>(deg, N, rowptr, bsums);
    scan_pass2<<<1, 64, 0, stream>>>(bsums, nb);
    scan_pass3<<<nb, 256, 0, stream>>>(rowptr, bsums, N, nb);
    dinv_kernel<<<(N + 255) / 256, 256, 0, stream>>>(deg, dinv, N);
    fill_csr_kernel<<<eb, 256, 0, stream>>>(srcIdx, dstIdx, E, rowptr, cursor, csr);

    int gb = (N + 63) / 64;  // 64 rows per block (4 waves x 16)
    int ab = (N + 3) / 4;    // 4 waves (nodes) per 256-thread block

    // layer 1
    gemm_mfma_kernel<<<gb, 256, 0, stream>>>(xb ? (const unsigned short*)xb : 0, Wt1, dinv, (unsigned short*)gbuf, N);
    aggregate_kernel<<<ab, 256, 0, stream>>>(gbuf, rowptr, csr, dinv, b1, hbuf, N);
    // layer 2
    gemm_mfma_kernel<<<gb, 256, 0, stream>>>((const unsigned short*)hbuf, Wt2, dinv, (unsigned short*)gbuf, N);
    aggregate_kernel<<<ab, 256, 0, stream>>>(gbuf, rowptr, csr, dinv, b2, hbuf, N);

    // pooling + LSTM + heads
    pool_partial_kernel<<<64 * POOL_SUB, 64, 0, stream>>>(hbuf, batch, N, partial);
    pool_finish_kernel<<<64, 128, 0, stream>>>(partial, batch, N, pooled);
    lstm_head_kernel<<<64, 256, 0, stream>>>(pooled, W_ih, b_ih, b_hh, Wm, bm, Wv, bv, out);
}

// Round 8
// 222.266 us; speedup vs baseline: 2.2437x; 1.0356x over previous
//
#include <hip/hip_runtime.h>
#include <hip/hip_bf16.h>
#include <math.h>

// ---------------------------------------------------------------------------
// GCN(2 layers, fused norm) -> mean-pool -> LSTM step (h0=c0=0) -> heads
// GEMMs via bf16 MFMA (f32 accum); gather/feature buffers bf16; reductions f32.
// ---------------------------------------------------------------------------

#define POOL_SUB 32

typedef __attribute__((ext_vector_type(8))) short bf16x8;
typedef __attribute__((ext_vector_type(4))) float f32x4;

static __device__ __forceinline__ unsigned short f2bf(float f) {
    union { float f; unsigned int u; } v; v.f = f;
    unsigned int u = v.u;
    unsigned int r = u + 0x7FFFu + ((u >> 16) & 1u);  // RNE
    return (unsigned short)(r >> 16);
}
static __device__ __forceinline__ unsigned int pack2bf(float lo, float hi) {
    return (unsigned int)f2bf(lo) | ((unsigned int)f2bf(hi) << 16);
}
static __device__ __forceinline__ float bflo(unsigned int v) {
    union { unsigned int u; float f; } w; w.u = v << 16; return w.f;
}
static __device__ __forceinline__ float bfhi(unsigned int v) {
    union { unsigned int u; float f; } w; w.u = v & 0xFFFF0000u; return w.f;
}
static __device__ __forceinline__ bf16x8 f8_to_bf(float4 f0, float4 f1) {
    union { unsigned int u[4]; bf16x8 v; } r;
    r.u[0] = pack2bf(f0.x, f0.y);
    r.u[1] = pack2bf(f0.z, f0.w);
    r.u[2] = pack2bf(f1.x, f1.y);
    r.u[3] = pack2bf(f1.z, f1.w);
    return r.v;
}

__global__ void zero_kernel(int* __restrict__ p, int n) {
    int i = blockIdx.x * blockDim.x + threadIdx.x;
    if (i < n) p[i] = 0;
}

__global__ void count_deg_kernel(const int* __restrict__ dst, int E, int* __restrict__ deg) {
    int e = blockIdx.x * blockDim.x + threadIdx.x;
    if (e < E) atomicAdd(&deg[dst[e]], 1);
}

// block scans 1024 elements (256 threads x 4)
__global__ void scan_pass1(const int* __restrict__ deg, int n,
                           int* __restrict__ rowptr, int* __restrict__ bsums) {
    __shared__ int s[256];
    int tid = threadIdx.x;
    int base = blockIdx.x * 1024;
    int v[4];
    int mysum = 0;
#pragma unroll
    for (int j = 0; j < 4; ++j) {
        int idx = base + tid * 4 + j;
        v[j] = (idx < n) ? deg[idx] : 0;
        mysum += v[j];
    }
    s[tid] = mysum;
    __syncthreads();
    for (int off = 1; off < 256; off <<= 1) {
        int t = (tid >= off) ? s[tid - off] : 0;
        __syncthreads();
        s[tid] += t;
        __syncthreads();
    }
    int excl = s[tid] - mysum;
#pragma unroll
    for (int j = 0; j < 4; ++j) {
        int idx = base + tid * 4 + j;
        if (idx < n) rowptr[idx] = excl;
        excl += v[j];
    }
    if (tid == 255) bsums[blockIdx.x] = s[255];
}

// scan up to 64 block sums (nb <= 64), exclusive; bsums[nb] = total
__global__ void scan_pass2(int* bsums, int nb) {
    __shared__ int s[64];
    int tid = threadIdx.x;
    int v = (tid < nb) ? bsums[tid] : 0;
    s[tid] = v;
    __syncthreads();
    for (int off = 1; off < 64; off <<= 1) {
        int t = (tid >= off) ? s[tid - off] : 0;
        __syncthreads();
        s[tid] += t;
        __syncthreads();
    }
    if (tid < nb) bsums[tid] = s[tid] - v;
    if (tid == 63) bsums[nb] = s[63];
}

// pass3 also computes dinv = rsqrt(deg+1)
__global__ void scan_pass3(int* __restrict__ rowptr, const int* __restrict__ bsums,
                           const int* __restrict__ deg, float* __restrict__ dinv,
                           int n, int nb) {
    int tid = threadIdx.x;
    int base = blockIdx.x * 1024;
    int add = bsums[blockIdx.x];
#pragma unroll
    for (int j = 0; j < 4; ++j) {
        int idx = base + tid * 4 + j;
        if (idx < n) {
            rowptr[idx] += add;
            dinv[idx] = rsqrtf((float)deg[idx] + 1.0f);
        }
    }
    if (blockIdx.x == 0 && tid == 0) rowptr[n] = bsums[nb];
}

__global__ void fill_csr_kernel(const int* __restrict__ src, const int* __restrict__ dst, int E,
                                const int* __restrict__ rowptr, int* __restrict__ cursor,
                                int* __restrict__ csr) {
    int e = blockIdx.x * blockDim.x + threadIdx.x;
    if (e < E) {
        int d = dst[e];
        int pos = rowptr[d] + atomicAdd(&cursor[d], 1);
        csr[pos] = src[e];
    }
}

// W (f32 [k][n] 128x128) -> Wt (bf16 [n][k]); blocks 0-127: W1, 128-255: W2
__global__ void wcvt_kernel(const float* __restrict__ W1, const float* __restrict__ W2,
                            unsigned short* __restrict__ Wt1, unsigned short* __restrict__ Wt2) {
    int nb = blockIdx.x & 127;
    const float* Ws = (blockIdx.x < 128) ? W1 : W2;
    unsigned short* Wd = (blockIdx.x < 128) ? Wt1 : Wt2;
    int k = threadIdx.x;
    Wd[nb * 128 + k] = f2bf(Ws[(size_t)k * 128 + nb]);
}

// out[r][c] = bf16( dinv[r] * sum_k A[r][k]*W[k][c] )
// 4 waves/block, wave: 16 rows x 128 cols, K=128 -> 32 mfma_f32_16x16x32_bf16.
// A/B use the same (lane,elem)->k mapping => any fixed bijection sums correctly;
// C/D layout: col = lane&15, row = (lane>>4)*4 + reg (HW-verified).
// f32-input variant (layer 1): converts x to bf16 in-register.
__global__ __launch_bounds__(256) void gemm_mfma_f32a_kernel(const float* __restrict__ A,
                                                             const unsigned short* __restrict__ Wt,
                                                             const float* __restrict__ dinv,
                                                             unsigned short* __restrict__ out,
                                                             int n) {
    int tid = threadIdx.x;
    int l = tid & 63;
    int wid = tid >> 6;
    int rowbase = blockIdx.x * 64 + wid * 16;
    int lc = l & 15;
    int kq = l >> 4;

    int arow = rowbase + lc; if (arow > n - 1) arow = n - 1;
    const float* Ap = A + (size_t)arow * 128 + kq * 8;
    const unsigned short* Wp = Wt + (size_t)lc * 128 + kq * 8;

    f32x4 acc[8];
#pragma unroll
    for (int c = 0; c < 8; ++c) acc[c] = (f32x4){0.f, 0.f, 0.f, 0.f};

#pragma unroll
    for (int ks = 0; ks < 4; ++ks) {
        float4 f0 = *(const float4*)(Ap + ks * 32);
        float4 f1 = *(const float4*)(Ap + ks * 32 + 4);
        bf16x8 a = f8_to_bf(f0, f1);
#pragma unroll
        for (int c = 0; c < 8; ++c) {
            bf16x8 b = *(const bf16x8*)(Wp + c * 2048 + ks * 32);
            acc[c] = __builtin_amdgcn_mfma_f32_16x16x32_bf16(a, b, acc[c], 0, 0, 0);
        }
    }

    int r0 = kq * 4;
    float s[4];
    int orow[4];
#pragma unroll
    for (int r = 0; r < 4; ++r) {
        orow[r] = rowbase + r0 + r;
        s[r] = (orow[r] < n) ? dinv[orow[r]] : 0.f;
    }
#pragma unroll
    for (int c = 0; c < 8; ++c) {
#pragma unroll
        for (int r = 0; r < 4; ++r) {
            if (orow[r] < n)
                out[(size_t)orow[r] * 128 + c * 16 + lc] = f2bf(acc[c][r] * s[r]);
        }
    }
}

// bf16-input variant (layer 2)
__global__ __launch_bounds__(256) void gemm_mfma_kernel(const unsigned short* __restrict__ A,
                                                        const unsigned short* __restrict__ Wt,
                                                        const float* __restrict__ dinv,
                                                        unsigned short* __restrict__ out,
                                                        int n) {
    int tid = threadIdx.x;
    int l = tid & 63;
    int wid = tid >> 6;
    int rowbase = blockIdx.x * 64 + wid * 16;
    int lc = l & 15;
    int kq = l >> 4;

    int arow = rowbase + lc; if (arow > n - 1) arow = n - 1;
    const unsigned short* Ap = A + (size_t)arow * 128 + kq * 8;
    const unsigned short* Wp = Wt + (size_t)lc * 128 + kq * 8;

    f32x4 acc[8];
#pragma unroll
    for (int c = 0; c < 8; ++c) acc[c] = (f32x4){0.f, 0.f, 0.f, 0.f};

#pragma unroll
    for (int ks = 0; ks < 4; ++ks) {
        bf16x8 a = *(const bf16x8*)(Ap + ks * 32);
#pragma unroll
        for (int c = 0; c < 8; ++c) {
            bf16x8 b = *(const bf16x8*)(Wp + c * 2048 + ks * 32);
            acc[c] = __builtin_amdgcn_mfma_f32_16x16x32_bf16(a, b, acc[c], 0, 0, 0);
        }
    }

    int r0 = kq * 4;
    float s[4];
    int orow[4];
#pragma unroll
    for (int r = 0; r < 4; ++r) {
        orow[r] = rowbase + r0 + r;
        s[r] = (orow[r] < n) ? dinv[orow[r]] : 0.f;
    }
#pragma unroll
    for (int c = 0; c < 8; ++c) {
#pragma unroll
        for (int r = 0; r < 4; ++r) {
            if (orow[r] < n)
                out[(size_t)orow[r] * 128 + c * 16 + lc] = f2bf(acc[c][r] * s[r]);
        }
    }
}

// out[i] = bf16( relu(dinv[i] * (sum_{e in in(i)} g[src_e] + g[i]) + bias) )
// g bf16 packed; one wave per node, lane owns one packed uint (2 features)
__global__ __launch_bounds__(256) void aggregate_kernel(const unsigned int* __restrict__ g,
                                                        const int* __restrict__ rowptr,
                                                        const int* __restrict__ csr,
                                                        const float* __restrict__ dinv,
                                                        const float* __restrict__ bias,
                                                        unsigned int* __restrict__ out, int n) {
    int lane = threadIdx.x & 63;
    int node = (blockIdx.x * blockDim.x + threadIdx.x) >> 6;
    if (node >= n) return;
    int beg = rowptr[node], end = rowptr[node + 1];
    unsigned int sv = g[(size_t)node * 64 + lane];  // self-loop term
    float ax = bflo(sv), ay = bfhi(sv);
    int e = beg;
    for (; e + 4 <= end; e += 4) {
        int s0 = csr[e + 0], s1 = csr[e + 1], s2 = csr[e + 2], s3 = csr[e + 3];
        unsigned int v0 = g[(size_t)s0 * 64 + lane];
        unsigned int v1 = g[(size_t)s1 * 64 + lane];
        unsigned int v2 = g[(size_t)s2 * 64 + lane];
        unsigned int v3 = g[(size_t)s3 * 64 + lane];
        ax += bflo(v0) + bflo(v1) + bflo(v2) + bflo(v3);
        ay += bfhi(v0) + bfhi(v1) + bfhi(v2) + bfhi(v3);
    }
    for (; e < end; ++e) {
        unsigned int v0 = g[(size_t)csr[e] * 64 + lane];
        ax += bflo(v0);
        ay += bfhi(v0);
    }
    float dv = dinv[node];
    float2 b = ((const float2*)bias)[lane];
    float rx = fmaxf(dv * ax + b.x, 0.f);
    float ry = fmaxf(dv * ay + b.y, 0.f);
    out[(size_t)node * 64 + lane] = pack2bf(rx, ry);
}

// stage 1: 64 graphs x POOL_SUB sub-blocks; 64 threads, 2 features each (bf16 in)
__global__ __launch_bounds__(64) void pool_partial_kernel(const unsigned int* __restrict__ h,
                                                          const int* __restrict__ batch, int n,
                                                          float* __restrict__ partial) {
    int g = blockIdx.x / POOL_SUB;
    int sub = blockIdx.x % POOL_SUB;
    int t = threadIdx.x;  // 0..63, packed pair t
    int lo = 0, hi = n;
    while (lo < hi) { int mid = (lo + hi) >> 1; if (batch[mid] < g) lo = mid + 1; else hi = mid; }
    int start = lo;
    hi = n;
    while (lo < hi) { int mid = (lo + hi) >> 1; if (batch[mid] < g + 1) lo = mid + 1; else hi = mid; }
    int end = lo;
    int len = end - start;
    int b0 = start + (int)((long long)len * sub / POOL_SUB);
    int b1 = start + (int)((long long)len * (sub + 1) / POOL_SUB);
    float ax = 0.f, ay = 0.f;
    int i = b0;
    for (; i + 4 <= b1; i += 4) {
        unsigned int v0 = h[(size_t)(i + 0) * 64 + t];
        unsigned int v1 = h[(size_t)(i + 1) * 64 + t];
        unsigned int v2 = h[(size_t)(i + 2) * 64 + t];
        unsigned int v3 = h[(size_t)(i + 3) * 64 + t];
        ax += bflo(v0) + bflo(v1) + bflo(v2) + bflo(v3);
        ay += bfhi(v0) + bfhi(v1) + bfhi(v2) + bfhi(v3);
    }
    for (; i < b1; ++i) {
        unsigned int v0 = h[(size_t)i * 64 + t];
        ax += bflo(v0);
        ay += bfhi(v0);
    }
    partial[(size_t)blockIdx.x * 128 + 2 * t]     = ax;
    partial[(size_t)blockIdx.x * 128 + 2 * t + 1] = ay;
}

// fused: pool finish (first 128 threads) + LSTM step + heads. 64 blocks x 256.
// gates order i,f,g,o ; f dead (c0=0), W_hh dead (h0=0).
__global__ __launch_bounds__(256) void pool_lstm_kernel(const float* __restrict__ partial,
                                                        const int* __restrict__ batch, int n,
                                                        const float* __restrict__ W_ih,
                                                        const float* __restrict__ b_ih,
                                                        const float* __restrict__ b_hh,
                                                        const float* __restrict__ Wm,
                                                        const float* __restrict__ bm,
                                                        const float* __restrict__ Wv,
                                                        const float* __restrict__ bv,
                                                        float* __restrict__ out) {
    __shared__ __align__(16) float p[128];
    __shared__ float redm[256];
    __shared__ float redv[256];
    int gph = blockIdx.x;
    int tid = threadIdx.x;
    if (tid < 128) {
        int lo = 0, hi = n;
        while (lo < hi) { int mid = (lo + hi) >> 1; if (batch[mid] < gph) lo = mid + 1; else hi = mid; }
        int start = lo;
        hi = n;
        while (lo < hi) { int mid = (lo + hi) >> 1; if (batch[mid] < gph + 1) lo = mid + 1; else hi = mid; }
        int end = lo;
        float acc = 0.f;
#pragma unroll
        for (int s = 0; s < POOL_SUB; ++s)
            acc += partial[(size_t)(gph * POOL_SUB + s) * 128 + tid];
        p[tid] = acc / fmaxf((float)(end - start), 1.0f);
    }
    __syncthreads();
    float gi = b_ih[tid] + b_hh[tid];
    float gg = b_ih[512 + tid] + b_hh[512 + tid];
    float go = b_ih[768 + tid] + b_hh[768 + tid];
    const float4* wi = (const float4*)(W_ih + (size_t)tid * 128);
    const float4* wg = (const float4*)(W_ih + (size_t)(512 + tid) * 128);
    const float4* wo = (const float4*)(W_ih + (size_t)(768 + tid) * 128);
    const float4* p4 = (const float4*)p;
#pragma unroll 8
    for (int k = 0; k < 32; ++k) {
        float4 xv = p4[k];
        float4 a = wi[k], bq = wg[k], cq = wo[k];
        gi += xv.x * a.x + xv.y * a.y + xv.z * a.z + xv.w * a.w;
        gg += xv.x * bq.x + xv.y * bq.y + xv.z * bq.z + xv.w * bq.w;
        go += xv.x * cq.x + xv.y * cq.y + xv.z * cq.z + xv.w * cq.w;
    }
    float iv = 1.f / (1.f + expf(-gi));
    float cv = iv * tanhf(gg);
    float ov = 1.f / (1.f + expf(-go));
    float hT = ov * tanhf(cv);
    redm[tid] = hT * Wm[tid];
    redv[tid] = hT * Wv[tid];
    __syncthreads();
    for (int s = 128; s > 0; s >>= 1) {
        if (tid < s) { redm[tid] += redm[tid + s]; redv[tid] += redv[tid + s]; }
        __syncthreads();
    }
    if (tid == 0) {
        out[gph] = redm[0] + bm[0];
        float xv = redv[0] + bv[0];
        out[64 + gph] = fmaxf(xv, 0.f) + log1pf(expf(-fabsf(xv)));  // stable softplus
    }
}

extern "C" void kernel_launch(void* const* d_in, const int* in_sizes, int n_in,
                              void* d_out, int out_size, void* d_ws, size_t ws_size,
                              hipStream_t stream) {
    const float* x     = (const float*)d_in[0];
    const int*   edge  = (const int*)d_in[1];
    const int*   batch = (const int*)d_in[2];
    const float* W1    = (const float*)d_in[3];
    const float* b1    = (const float*)d_in[4];
    const float* W2    = (const float*)d_in[5];
    const float* b2    = (const float*)d_in[6];
    const float* W_ih  = (const float*)d_in[7];
    /* d_in[8] = W_hh: dead (h0 = 0) */
    const float* b_ih  = (const float*)d_in[9];
    const float* b_hh  = (const float*)d_in[10];
    const float* Wm    = (const float*)d_in[11];
    const float* bm    = (const float*)d_in[12];
    const float* Wv    = (const float*)d_in[13];
    const float* bv    = (const float*)d_in[14];
    float* out = (float*)d_out;

    const int N = in_sizes[0] / 128;
    const int E = in_sizes[1] / 2;
    const int* srcIdx = edge;      // edge_index[0]
    const int* dstIdx = edge + E;  // edge_index[1]

    char* ws = (char*)d_ws;
    size_t off = 0;
    const size_t gB = (size_t)N * 64 * sizeof(unsigned int);  // bf16 N x 128
    unsigned int* gbuf = (unsigned int*)(ws + off); off += gB;
    unsigned int* hbuf = (unsigned int*)(ws + off); off += gB;
    int* deg    = (int*)(ws + off);   off += (size_t)N * sizeof(int);
    int* cursor = (int*)(ws + off);   off += (size_t)N * sizeof(int);  // adjacent to deg
    int* rowptr = (int*)(ws + off);   off += (size_t)(N + 1) * sizeof(int);
    off = (off + 255) & ~(size_t)255;
    int* bsums  = (int*)(ws + off);   off += 512;
    int* csr    = (int*)(ws + off);   off += (size_t)E * sizeof(int);
    off = (off + 255) & ~(size_t)255;
    float* dinv = (float*)(ws + off); off += (size_t)N * sizeof(float);
    off = (off + 255) & ~(size_t)255;
    unsigned short* Wt1 = (unsigned short*)(ws + off); off += 128 * 128 * sizeof(unsigned short);
    unsigned short* Wt2 = (unsigned short*)(ws + off); off += 128 * 128 * sizeof(unsigned short);
    off = (off + 255) & ~(size_t)255;
    float* partial = (float*)(ws + off); off += (size_t)64 * POOL_SUB * 128 * sizeof(float);

    // zero deg + cursor (contiguous, own kernel: keep rocclr fill out of graph)
    zero_kernel<<<(2 * N + 255) / 256, 256, 0, stream>>>(deg, 2 * N);

    wcvt_kernel<<<256, 128, 0, stream>>>(W1, W2, Wt1, Wt2);

    int eb = (E + 255) / 256;
    count_deg_kernel<<<eb, 256, 0, stream>>>(dstIdx, E, deg);

    int nb = (N + 1023) / 1024;  // 49 for N=50000 (<=64 required by scan_pass2)
    scan_pass1<<<nb, 256, 0, stream>>>(deg, N, rowptr, bsums);
    scan_pass2<<<1, 64, 0, stream>>>(bsums, nb);
    scan_pass3<<<nb, 256, 0, stream>>>(rowptr, bsums, deg, dinv, N, nb);
    fill_csr_kernel<<<eb, 256, 0, stream>>>(srcIdx, dstIdx, E, rowptr, cursor, csr);

    int gb = (N + 63) / 64;  // 64 rows per block (4 waves x 16)
    int ab = (N + 3) / 4;    // 4 waves (nodes) per 256-thread block

    // layer 1 (f32 x read directly, converted in-register)
    gemm_mfma_f32a_kernel<<<gb, 256, 0, stream>>>(x, Wt1, dinv, (unsigned short*)gbuf, N);
    aggregate_kernel<<<ab, 256, 0, stream>>>(gbuf, rowptr, csr, dinv, b1, hbuf, N);
    // layer 2
    gemm_mfma_kernel<<<gb, 256, 0, stream>>>((const unsigned short*)hbuf, Wt2, dinv, (unsigned short*)gbuf, N);
    aggregate_kernel<<<ab, 256, 0, stream>>>(gbuf, rowptr, csr, dinv, b2, hbuf, N);

    // pooling + fused finish+LSTM+heads
    pool_partial_kernel<<<64 * POOL_SUB, 64, 0, stream>>>(hbuf, batch, N, partial);
    pool_lstm_kernel<<<64, 256, 0, stream>>>(partial, batch, N, W_ih, b_ih, b_hh, Wm, bm, Wv, bv, out);
}